// Round 3
// baseline (6504.757 us; speedup 1.0000x reference)
//
#include <hip/hip_runtime.h>
#include <hip/hip_bf16.h>

#define BB 16
#define LQ 1025
#define FF 768
#define HH 12
#define DD 64
#define EPSF 1e-8f

typedef unsigned short u16;

__device__ __forceinline__ float bf2f(u16 u) {
    union { unsigned int i; float f; } c;
    c.i = ((unsigned int)u) << 16;
    return c.f;
}

__device__ __forceinline__ u16 f2bf(float f) {
    union { float f; unsigned int i; } c;
    c.f = f;
    unsigned int x = c.i;
    unsigned int r = (x + 0x7fffu + ((x >> 16) & 1u)) >> 16;  // round-nearest-even
    return (u16)r;
}

// ---------------------------------------------------------------------------
// Kernel 1: fused QKV projection. fp32 inputs.
//   A = x [M=B*L][K=768] fp32 row-major, W = wq/wk/wv [768][H*D=768] fp32.
//   Tile 64x64, block 256 threads, 4x4 microtile, BK=16, fp32 accumulate.
//   blockIdx.y == h (N-tile == one head), blockIdx.z == {q,k,v}.
//   Epilogue: +bias, then q: relu(x/8)+eps, k: relu(x)+eps, v: identity.
//   Output layout [B][H][L][D] bf16 for attention locality.
// ---------------------------------------------------------------------------
__global__ __launch_bounds__(256) void gemm_qkv(
    const float* __restrict__ x,
    const float* __restrict__ wq, const float* __restrict__ bq,
    const float* __restrict__ wk, const float* __restrict__ bk,
    const float* __restrict__ wv, const float* __restrict__ bv,
    u16* __restrict__ qbuf, u16* __restrict__ kbuf, u16* __restrict__ vbuf)
{
    const int M = BB * LQ;  // 16400
    const int type = blockIdx.z;
    const float* __restrict__ w    = (type == 0) ? wq : (type == 1) ? wk : wv;
    const float* __restrict__ bias = (type == 0) ? bq : (type == 1) ? bk : bv;
    u16* __restrict__ outb         = (type == 0) ? qbuf : (type == 1) ? kbuf : vbuf;

    const int m0 = blockIdx.x * 64;
    const int h  = blockIdx.y;      // n0 = h*64
    const int n0 = h * 64;

    __shared__ float As[16][64];  // [k][m]
    __shared__ float Bs[16][64];  // [k][n]

    const int t = threadIdx.x;
    const int am = t >> 2;          // 0..63
    const int ak = (t & 3) << 2;    // 0,4,8,12
    const int kb = t >> 4;          // 0..15
    const int nb = (t & 15) << 2;   // 0..60
    const int tmb = (t >> 4) << 2;  // m offset 0..60
    const int tnb = (t & 15) << 2;  // n offset 0..60

    float acc[4][4] = {{0.f}};

    for (int k0 = 0; k0 < 768; k0 += 16) {
        __syncthreads();
        // stage A
        {
            int gm = m0 + am;
            if (gm < M) {
                float4 u = *(const float4*)(x + (size_t)gm * 768 + k0 + ak);
                As[ak + 0][am] = u.x;
                As[ak + 1][am] = u.y;
                As[ak + 2][am] = u.z;
                As[ak + 3][am] = u.w;
            } else {
                As[ak + 0][am] = 0.f;
                As[ak + 1][am] = 0.f;
                As[ak + 2][am] = 0.f;
                As[ak + 3][am] = 0.f;
            }
        }
        // stage B
        {
            float4 u = *(const float4*)(w + (size_t)(k0 + kb) * 768 + n0 + nb);
            Bs[kb][nb + 0] = u.x;
            Bs[kb][nb + 1] = u.y;
            Bs[kb][nb + 2] = u.z;
            Bs[kb][nb + 3] = u.w;
        }
        __syncthreads();
#pragma unroll
        for (int kk = 0; kk < 16; ++kk) {
            float4 a4 = *(const float4*)&As[kk][tmb];
            float4 b4 = *(const float4*)&Bs[kk][tnb];
            float av[4] = {a4.x, a4.y, a4.z, a4.w};
            float bv4[4] = {b4.x, b4.y, b4.z, b4.w};
#pragma unroll
            for (int i = 0; i < 4; ++i)
#pragma unroll
                for (int j = 0; j < 4; ++j)
                    acc[i][j] += av[i] * bv4[j];
        }
    }

    // epilogue
#pragma unroll
    for (int i = 0; i < 4; ++i) {
        int gm = m0 + tmb + i;
        if (gm >= M) continue;
        int b_idx = gm / LQ;
        int l     = gm - b_idx * LQ;
#pragma unroll
        for (int j = 0; j < 4; ++j) {
            int d = tnb + j;
            float v = acc[i][j] + bias[n0 + d];
            if (type == 0) v = fmaxf(v * 0.125f, 0.f) + EPSF;        // q: relu(q/8)+eps
            else if (type == 1) v = fmaxf(v, 0.f) + EPSF;            // k: relu(k)+eps
            outb[((size_t)(b_idx * HH + h) * LQ + l) * 64 + d] = f2bf(v);
        }
    }
}

// ---------------------------------------------------------------------------
// Kernel 2: fused attention (sum-normalized relu kernel + Toeplitz mask).
//   grid (33 q-tiles, B*H). block 256.
//   q/k/v in bf16 workspace; tp (toeplitz_params) fp32 [H][4096].
// ---------------------------------------------------------------------------
__global__ __launch_bounds__(256) void attn_fused(
    const u16* __restrict__ qbuf, const u16* __restrict__ kbuf,
    const u16* __restrict__ vbuf, const float* __restrict__ tp,
    u16* __restrict__ obuf)
{
    const int bh = blockIdx.y;          // b*H + h
    const int b  = bh / HH;
    const int h  = bh - b * HH;
    const int q0 = blockIdx.x * 32;

    __shared__ float Qs[32][64];
    __shared__ float Ks[32][64];
    __shared__ float Vs[32][64];
    __shared__ float Ss[32][32];

    const int t   = threadIdx.x;
    const int row = t >> 3;             // 0..31
    const int dsb = (t & 7) << 3;       // 0..56
    const int r   = t >> 3;             // q-row within tile
    const int c   = t & 7;              // score-column group / d-column group

    const size_t base = (size_t)bh * LQ * 64;

    // load Q tile
    {
        int qi = q0 + row;
        if (qi < LQ) {
            const u16* p = qbuf + base + (size_t)qi * 64 + dsb;
            ushort4 u0 = *(const ushort4*)p;
            ushort4 u1 = *(const ushort4*)(p + 4);
            Qs[row][dsb + 0] = bf2f(u0.x); Qs[row][dsb + 1] = bf2f(u0.y);
            Qs[row][dsb + 2] = bf2f(u0.z); Qs[row][dsb + 3] = bf2f(u0.w);
            Qs[row][dsb + 4] = bf2f(u1.x); Qs[row][dsb + 5] = bf2f(u1.y);
            Qs[row][dsb + 6] = bf2f(u1.z); Qs[row][dsb + 7] = bf2f(u1.w);
        } else {
#pragma unroll
            for (int j = 0; j < 8; ++j) Qs[row][dsb + j] = 0.f;
        }
    }

    float num[8] = {0.f, 0.f, 0.f, 0.f, 0.f, 0.f, 0.f, 0.f};
    float den = 0.f;

    const int qi  = q0 + r;
    const bool qvalid = (qi < LQ);
    int gqi = 0, gqj = 0;
    const bool qcls = (qi == 0);
    if (qvalid && !qcls) { gqi = (qi - 1) >> 5; gqj = (qi - 1) & 31; }

    for (int kt = 0; kt < 33; ++kt) {
        const int k0 = kt * 32;
        __syncthreads();   // protect previous iteration's Ks/Vs/Ss reads
        // stage K,V tiles
        {
            int ki = k0 + row;
            if (ki < LQ) {
                const u16* kp = kbuf + base + (size_t)ki * 64 + dsb;
                const u16* vp = vbuf + base + (size_t)ki * 64 + dsb;
                ushort4 ku0 = *(const ushort4*)kp;
                ushort4 ku1 = *(const ushort4*)(kp + 4);
                ushort4 vu0 = *(const ushort4*)vp;
                ushort4 vu1 = *(const ushort4*)(vp + 4);
                Ks[row][dsb + 0] = bf2f(ku0.x); Ks[row][dsb + 1] = bf2f(ku0.y);
                Ks[row][dsb + 2] = bf2f(ku0.z); Ks[row][dsb + 3] = bf2f(ku0.w);
                Ks[row][dsb + 4] = bf2f(ku1.x); Ks[row][dsb + 5] = bf2f(ku1.y);
                Ks[row][dsb + 6] = bf2f(ku1.z); Ks[row][dsb + 7] = bf2f(ku1.w);
                Vs[row][dsb + 0] = bf2f(vu0.x); Vs[row][dsb + 1] = bf2f(vu0.y);
                Vs[row][dsb + 2] = bf2f(vu0.z); Vs[row][dsb + 3] = bf2f(vu0.w);
                Vs[row][dsb + 4] = bf2f(vu1.x); Vs[row][dsb + 5] = bf2f(vu1.y);
                Vs[row][dsb + 6] = bf2f(vu1.z); Vs[row][dsb + 7] = bf2f(vu1.w);
            } else {
#pragma unroll
                for (int j = 0; j < 8; ++j) { Ks[row][dsb + j] = 0.f; Vs[row][dsb + j] = 0.f; }
            }
        }
        __syncthreads();

        // scores: thread computes 4 columns kk = c*4..c*4+3 of its row r
        {
            float s[4] = {0.f, 0.f, 0.f, 0.f};
            for (int d4 = 0; d4 < 64; d4 += 4) {
                float4 qv = *(const float4*)&Qs[r][d4];
#pragma unroll
                for (int j = 0; j < 4; ++j) {
                    float4 kv = *(const float4*)&Ks[c * 4 + j][d4];
                    s[j] += qv.x * kv.x + qv.y * kv.y + qv.z * kv.z + qv.w * kv.w;
                }
            }
#pragma unroll
            for (int j = 0; j < 4; ++j) {
                int ki = k0 + c * 4 + j;
                float sv;
                if (!qvalid || ki >= LQ) {
                    sv = 0.f;   // nonexistent key/query contributes nothing
                } else {
                    float tmv;
                    if (qcls || ki == 0) {
                        tmv = 1.f;
                    } else {
                        int gki = (ki - 1) >> 5;
                        int gkj = (ki - 1) & 31;
                        int idx = ((gqi - gki + 32) << 6) + (gqj - gkj + 32);
                        tmv = fabsf(tp[h * 4096 + idx]);
                    }
                    sv = s[j] * tmv + EPSF;
                }
                Ss[r][c * 4 + j] = sv;
            }
        }
        __syncthreads();

        // accumulate num/den over this key tile
        {
            const int dbase = c * 8;
#pragma unroll
            for (int kk = 0; kk < 32; ++kk) {
                float sv = Ss[r][kk];
                den += sv;
                float4 v0 = *(const float4*)&Vs[kk][dbase];
                float4 v1 = *(const float4*)&Vs[kk][dbase + 4];
                num[0] += sv * v0.x; num[1] += sv * v0.y;
                num[2] += sv * v0.z; num[3] += sv * v0.w;
                num[4] += sv * v1.x; num[5] += sv * v1.y;
                num[6] += sv * v1.z; num[7] += sv * v1.w;
            }
        }
    }

    // write out: obuf layout [B][L][H][D] (reads as [M][768] in out-proj GEMM)
    if (qvalid) {
        float inv = 1.f / den;
        u16* p = obuf + ((size_t)(b * LQ + qi) * HH + h) * 64 + c * 8;
#pragma unroll
        for (int j = 0; j < 8; ++j) p[j] = f2bf(num[j] * inv);
    }
}

// ---------------------------------------------------------------------------
// Kernel 3: output projection. A = obuf [M][768] bf16, W = wo [768][768] fp32,
// +bo, out fp32 [M][768]. Same tiling as kernel 1.
// ---------------------------------------------------------------------------
__global__ __launch_bounds__(256) void gemm_out(
    const u16* __restrict__ a, const float* __restrict__ w,
    const float* __restrict__ bo, float* __restrict__ out)
{
    const int M = BB * LQ;
    const int m0 = blockIdx.x * 64;
    const int n0 = blockIdx.y * 64;

    __shared__ float As[16][64];
    __shared__ float Bs[16][64];

    const int t = threadIdx.x;
    const int am = t >> 2;
    const int ak = (t & 3) << 2;
    const int kb = t >> 4;
    const int nb = (t & 15) << 2;
    const int tmb = (t >> 4) << 2;
    const int tnb = (t & 15) << 2;

    float acc[4][4] = {{0.f}};

    for (int k0 = 0; k0 < 768; k0 += 16) {
        __syncthreads();
        {
            int gm = m0 + am;
            if (gm < M) {
                const u16* p = a + (size_t)gm * 768 + k0 + ak;
                ushort4 u = *(const ushort4*)p;
                As[ak + 0][am] = bf2f(u.x);
                As[ak + 1][am] = bf2f(u.y);
                As[ak + 2][am] = bf2f(u.z);
                As[ak + 3][am] = bf2f(u.w);
            } else {
                As[ak + 0][am] = 0.f; As[ak + 1][am] = 0.f;
                As[ak + 2][am] = 0.f; As[ak + 3][am] = 0.f;
            }
        }
        {
            float4 u = *(const float4*)(w + (size_t)(k0 + kb) * 768 + n0 + nb);
            Bs[kb][nb + 0] = u.x;
            Bs[kb][nb + 1] = u.y;
            Bs[kb][nb + 2] = u.z;
            Bs[kb][nb + 3] = u.w;
        }
        __syncthreads();
#pragma unroll
        for (int kk = 0; kk < 16; ++kk) {
            float4 a4 = *(const float4*)&As[kk][tmb];
            float4 b4 = *(const float4*)&Bs[kk][tnb];
            float av[4] = {a4.x, a4.y, a4.z, a4.w};
            float bv4[4] = {b4.x, b4.y, b4.z, b4.w};
#pragma unroll
            for (int i = 0; i < 4; ++i)
#pragma unroll
                for (int j = 0; j < 4; ++j)
                    acc[i][j] += av[i] * bv4[j];
        }
    }

#pragma unroll
    for (int i = 0; i < 4; ++i) {
        int gm = m0 + tmb + i;
        if (gm >= M) continue;
#pragma unroll
        for (int j = 0; j < 4; ++j) {
            int n = n0 + tnb + j;
            out[(size_t)gm * 768 + n] = acc[i][j] + bo[n];
        }
    }
}

extern "C" void kernel_launch(void* const* d_in, const int* in_sizes, int n_in,
                              void* d_out, int out_size, void* d_ws, size_t ws_size,
                              hipStream_t stream) {
    const float* x  = (const float*)d_in[0];
    const float* wq = (const float*)d_in[1];
    const float* bq = (const float*)d_in[2];
    const float* wk = (const float*)d_in[3];
    const float* bk = (const float*)d_in[4];
    const float* wv = (const float*)d_in[5];
    const float* bv = (const float*)d_in[6];
    const float* wo = (const float*)d_in[7];
    const float* bo = (const float*)d_in[8];
    const float* tp = (const float*)d_in[9];
    float* out = (float*)d_out;

    const size_t per = (size_t)BB * HH * LQ * DD;  // 12,595,200
    u16* qbuf = (u16*)d_ws;
    u16* kbuf = qbuf + per;
    u16* vbuf = kbuf + per;
    u16* obuf = vbuf + per;   // [B][L][H][D]

    dim3 g1(257, 12, 3);
    gemm_qkv<<<g1, 256, 0, stream>>>(x, wq, bq, wk, bk, wv, bv, qbuf, kbuf, vbuf);

    dim3 g2(33, BB * HH);
    attn_fused<<<g2, 256, 0, stream>>>(qbuf, kbuf, vbuf, tp, obuf);

    dim3 g3(257, 12);
    gemm_out<<<g3, 256, 0, stream>>>(obuf, wo, bo, out);
}

// Round 4
// 2338.794 us; speedup vs baseline: 2.7812x; 2.7812x over previous
//
#include <hip/hip_runtime.h>
#include <hip/hip_bf16.h>

#define BB 16
#define LQ 1025
#define FF 768
#define HH 12
#define DD 64
#define EPSF 1e-8f

typedef unsigned short u16;

__device__ __forceinline__ float bf2f(u16 u) {
    union { unsigned int i; float f; } c;
    c.i = ((unsigned int)u) << 16;
    return c.f;
}

__device__ __forceinline__ u16 f2bf(float f) {
    union { float f; unsigned int i; } c;
    c.f = f;
    unsigned int x = c.i;
    unsigned int r = (x + 0x7fffu + ((x >> 16) & 1u)) >> 16;  // round-nearest-even
    return (u16)r;
}

// ---------------------------------------------------------------------------
// Kernel 1: fused QKV projection. fp32 inputs. (unchanged from passing R3)
// ---------------------------------------------------------------------------
__global__ __launch_bounds__(256) void gemm_qkv(
    const float* __restrict__ x,
    const float* __restrict__ wq, const float* __restrict__ bq,
    const float* __restrict__ wk, const float* __restrict__ bk,
    const float* __restrict__ wv, const float* __restrict__ bv,
    u16* __restrict__ qbuf, u16* __restrict__ kbuf, u16* __restrict__ vbuf)
{
    const int M = BB * LQ;  // 16400
    const int type = blockIdx.z;
    const float* __restrict__ w    = (type == 0) ? wq : (type == 1) ? wk : wv;
    const float* __restrict__ bias = (type == 0) ? bq : (type == 1) ? bk : bv;
    u16* __restrict__ outb         = (type == 0) ? qbuf : (type == 1) ? kbuf : vbuf;

    const int m0 = blockIdx.x * 64;
    const int h  = blockIdx.y;
    const int n0 = h * 64;

    __shared__ float As[16][64];
    __shared__ float Bs[16][64];

    const int t = threadIdx.x;
    const int am = t >> 2;
    const int ak = (t & 3) << 2;
    const int kb = t >> 4;
    const int nb = (t & 15) << 2;
    const int tmb = (t >> 4) << 2;
    const int tnb = (t & 15) << 2;

    float acc[4][4] = {{0.f}};

    for (int k0 = 0; k0 < 768; k0 += 16) {
        __syncthreads();
        {
            int gm = m0 + am;
            if (gm < M) {
                float4 u = *(const float4*)(x + (size_t)gm * 768 + k0 + ak);
                As[ak + 0][am] = u.x;
                As[ak + 1][am] = u.y;
                As[ak + 2][am] = u.z;
                As[ak + 3][am] = u.w;
            } else {
                As[ak + 0][am] = 0.f;
                As[ak + 1][am] = 0.f;
                As[ak + 2][am] = 0.f;
                As[ak + 3][am] = 0.f;
            }
        }
        {
            float4 u = *(const float4*)(w + (size_t)(k0 + kb) * 768 + n0 + nb);
            Bs[kb][nb + 0] = u.x;
            Bs[kb][nb + 1] = u.y;
            Bs[kb][nb + 2] = u.z;
            Bs[kb][nb + 3] = u.w;
        }
        __syncthreads();
#pragma unroll
        for (int kk = 0; kk < 16; ++kk) {
            float4 a4 = *(const float4*)&As[kk][tmb];
            float4 b4 = *(const float4*)&Bs[kk][tnb];
            float av[4] = {a4.x, a4.y, a4.z, a4.w};
            float bv4[4] = {b4.x, b4.y, b4.z, b4.w};
#pragma unroll
            for (int i = 0; i < 4; ++i)
#pragma unroll
                for (int j = 0; j < 4; ++j)
                    acc[i][j] += av[i] * bv4[j];
        }
    }

#pragma unroll
    for (int i = 0; i < 4; ++i) {
        int gm = m0 + tmb + i;
        if (gm >= M) continue;
        int b_idx = gm / LQ;
        int l     = gm - b_idx * LQ;
#pragma unroll
        for (int j = 0; j < 4; ++j) {
            int d = tnb + j;
            float v = acc[i][j] + bias[n0 + d];
            if (type == 0) v = fmaxf(v * 0.125f, 0.f) + EPSF;
            else if (type == 1) v = fmaxf(v, 0.f) + EPSF;
            outb[((size_t)(b_idx * HH + h) * LQ + l) * 64 + d] = f2bf(v);
        }
    }
}

// ---------------------------------------------------------------------------
// Kernel 2: fused attention, conflict-free LDS layout.
//   grid (17 q-tiles of 64, B*H), block 256.
//   Q/K/V tiles in LDS as bf16 [64][72] (pitch 72 u16 -> bank stride 4;
//   staging is raw uint4 copies). Scores Ss[64][68] fp32 (pitch 68).
//   Thread (rg = t>>4, cg = t&15): scores for rows {rg+16i} x cols {cg+16j};
//   PV for rows {rg+16i} x d-cols {4cg..4cg+3}. Interleaved (stride-1) row
//   assignment keeps all wave LDS accesses <=2-way (free).
// ---------------------------------------------------------------------------
__global__ __launch_bounds__(256) void attn_fused(
    const u16* __restrict__ qbuf, const u16* __restrict__ kbuf,
    const u16* __restrict__ vbuf, const float* __restrict__ tp,
    u16* __restrict__ obuf)
{
    const int bh = blockIdx.y;          // b*H + h
    const int b  = bh / HH;
    const int h  = bh - b * HH;
    const int q0 = blockIdx.x * 64;

    __shared__ u16   QsU[64][72];
    __shared__ u16   KsU[64][72];
    __shared__ u16   VsU[64][72];
    __shared__ float Ss[64][68];

    const int t  = threadIdx.x;
    const int rg = t >> 4;              // 0..15
    const int cg = t & 15;              // 0..15

    const size_t base = (size_t)bh * LQ * 64;

    // ---- stage Q tile (raw bf16 copy) ----
    {
        const int row = t >> 2;          // 0..63
        const int s0  = (t & 3) << 4;    // 0,16,32,48 (u16 elems)
        const int qi = q0 + row;
        if (qi < LQ) {
            const uint4* qp = (const uint4*)(qbuf + base + (size_t)qi * 64 + s0);
            *(uint4*)&QsU[row][s0]     = qp[0];
            *(uint4*)&QsU[row][s0 + 8] = qp[1];
        } else {
            uint4 z; z.x = 0; z.y = 0; z.z = 0; z.w = 0;
            *(uint4*)&QsU[row][s0]     = z;
            *(uint4*)&QsU[row][s0 + 8] = z;
        }
    }

    // per-row query metadata
    int  qi_[4];
    int  gqi_[4], gqj_[4];
    bool qv_[4], qc_[4];
#pragma unroll
    for (int i = 0; i < 4; ++i) {
        int qi = q0 + rg + 16 * i;
        qi_[i] = qi;
        qv_[i] = (qi < LQ);
        qc_[i] = (qi == 0);
        int qm1 = qi - 1;
        gqi_[i] = (qv_[i] && !qc_[i]) ? (qm1 >> 5) : 0;
        gqj_[i] = (qv_[i] && !qc_[i]) ? (qm1 & 31) : 0;
    }

    float num[4][4] = {{0.f}};
    float den[4]    = {0.f, 0.f, 0.f, 0.f};

    for (int kt = 0; kt < 17; ++kt) {
        const int k0 = kt * 64;
        __syncthreads();   // protect prev Ks/Vs reads (and Q staging on kt=0)

        // ---- stage K,V tiles (raw bf16 copies) ----
        {
            const int row = t >> 2;
            const int s0  = (t & 3) << 4;
            const int ki = k0 + row;
            if (ki < LQ) {
                const uint4* kp = (const uint4*)(kbuf + base + (size_t)ki * 64 + s0);
                const uint4* vp = (const uint4*)(vbuf + base + (size_t)ki * 64 + s0);
                *(uint4*)&KsU[row][s0]     = kp[0];
                *(uint4*)&KsU[row][s0 + 8] = kp[1];
                *(uint4*)&VsU[row][s0]     = vp[0];
                *(uint4*)&VsU[row][s0 + 8] = vp[1];
            } else {
                uint4 z; z.x = 0; z.y = 0; z.z = 0; z.w = 0;
                *(uint4*)&KsU[row][s0]     = z;
                *(uint4*)&KsU[row][s0 + 8] = z;
                *(uint4*)&VsU[row][s0]     = z;
                *(uint4*)&VsU[row][s0 + 8] = z;
            }
        }
        __syncthreads();

        // ---- scores: 4 rows x 4 cols per thread ----
        {
            float s[4][4] = {{0.f}};
#pragma unroll 4
            for (int d4 = 0; d4 < 64; d4 += 4) {
                float q4[4][4], k4[4][4];
#pragma unroll
                for (int i = 0; i < 4; ++i) {
                    ushort4 u = *(const ushort4*)&QsU[rg + 16 * i][d4];
                    q4[i][0] = bf2f(u.x); q4[i][1] = bf2f(u.y);
                    q4[i][2] = bf2f(u.z); q4[i][3] = bf2f(u.w);
                }
#pragma unroll
                for (int j = 0; j < 4; ++j) {
                    ushort4 u = *(const ushort4*)&KsU[cg + 16 * j][d4];
                    k4[j][0] = bf2f(u.x); k4[j][1] = bf2f(u.y);
                    k4[j][2] = bf2f(u.z); k4[j][3] = bf2f(u.w);
                }
#pragma unroll
                for (int i = 0; i < 4; ++i)
#pragma unroll
                    for (int j = 0; j < 4; ++j)
                        s[i][j] += q4[i][0] * k4[j][0] + q4[i][1] * k4[j][1]
                                 + q4[i][2] * k4[j][2] + q4[i][3] * k4[j][3];
            }
            // mask + eps, write Ss
#pragma unroll
            for (int j = 0; j < 4; ++j) {
                int ki = k0 + cg + 16 * j;
                bool kvalid = (ki < LQ);
                bool kcls   = (ki == 0);
                int gki = 0, gkj = 0;
                if (kvalid && !kcls) { gki = (ki - 1) >> 5; gkj = (ki - 1) & 31; }
#pragma unroll
                for (int i = 0; i < 4; ++i) {
                    float sv = 0.f;
                    if (qv_[i] && kvalid) {
                        float tm = 1.f;
                        if (!qc_[i] && !kcls) {
                            int idx = ((gqi_[i] - gki + 32) << 6) + (gqj_[i] - gkj + 32);
                            tm = fabsf(tp[h * 4096 + idx]);
                        }
                        sv = s[i][j] * tm + EPSF;
                    }
                    Ss[rg + 16 * i][cg + 16 * j] = sv;
                }
            }
        }
        __syncthreads();

        // ---- PV accumulate: 4 rows x 4 d-cols per thread ----
        {
            const int d0 = cg << 2;
#pragma unroll 4
            for (int kk = 0; kk < 64; kk += 4) {
                float v[4][4];
#pragma unroll
                for (int tt = 0; tt < 4; ++tt) {
                    ushort4 u = *(const ushort4*)&VsU[kk + tt][d0];
                    v[tt][0] = bf2f(u.x); v[tt][1] = bf2f(u.y);
                    v[tt][2] = bf2f(u.z); v[tt][3] = bf2f(u.w);
                }
#pragma unroll
                for (int i = 0; i < 4; ++i) {
                    float4 s4 = *(const float4*)&Ss[rg + 16 * i][kk];
                    den[i] += (s4.x + s4.y) + (s4.z + s4.w);
#pragma unroll
                    for (int jd = 0; jd < 4; ++jd)
                        num[i][jd] += s4.x * v[0][jd] + s4.y * v[1][jd]
                                    + s4.z * v[2][jd] + s4.w * v[3][jd];
                }
            }
        }
    }

    // ---- write out: obuf [B][L][H][D] bf16 ----
#pragma unroll
    for (int i = 0; i < 4; ++i) {
        if (!qv_[i]) continue;
        float inv = 1.f / den[i];
        ushort4 o;
        o.x = f2bf(num[i][0] * inv);
        o.y = f2bf(num[i][1] * inv);
        o.z = f2bf(num[i][2] * inv);
        o.w = f2bf(num[i][3] * inv);
        u16* p = obuf + ((size_t)(b * LQ + qi_[i]) * HH + h) * 64 + (cg << 2);
        *(ushort4*)p = o;
    }
}

// ---------------------------------------------------------------------------
// Kernel 3: output projection. (unchanged from passing R3)
// ---------------------------------------------------------------------------
__global__ __launch_bounds__(256) void gemm_out(
    const u16* __restrict__ a, const float* __restrict__ w,
    const float* __restrict__ bo, float* __restrict__ out)
{
    const int M = BB * LQ;
    const int m0 = blockIdx.x * 64;
    const int n0 = blockIdx.y * 64;

    __shared__ float As[16][64];
    __shared__ float Bs[16][64];

    const int t = threadIdx.x;
    const int am = t >> 2;
    const int ak = (t & 3) << 2;
    const int kb = t >> 4;
    const int nb = (t & 15) << 2;
    const int tmb = (t >> 4) << 2;
    const int tnb = (t & 15) << 2;

    float acc[4][4] = {{0.f}};

    for (int k0 = 0; k0 < 768; k0 += 16) {
        __syncthreads();
        {
            int gm = m0 + am;
            if (gm < M) {
                const u16* p = a + (size_t)gm * 768 + k0 + ak;
                ushort4 u = *(const ushort4*)p;
                As[ak + 0][am] = bf2f(u.x);
                As[ak + 1][am] = bf2f(u.y);
                As[ak + 2][am] = bf2f(u.z);
                As[ak + 3][am] = bf2f(u.w);
            } else {
                As[ak + 0][am] = 0.f; As[ak + 1][am] = 0.f;
                As[ak + 2][am] = 0.f; As[ak + 3][am] = 0.f;
            }
        }
        {
            float4 u = *(const float4*)(w + (size_t)(k0 + kb) * 768 + n0 + nb);
            Bs[kb][nb + 0] = u.x;
            Bs[kb][nb + 1] = u.y;
            Bs[kb][nb + 2] = u.z;
            Bs[kb][nb + 3] = u.w;
        }
        __syncthreads();
#pragma unroll
        for (int kk = 0; kk < 16; ++kk) {
            float4 a4 = *(const float4*)&As[kk][tmb];
            float4 b4 = *(const float4*)&Bs[kk][tnb];
            float av[4] = {a4.x, a4.y, a4.z, a4.w};
            float bv4[4] = {b4.x, b4.y, b4.z, b4.w};
#pragma unroll
            for (int i = 0; i < 4; ++i)
#pragma unroll
                for (int j = 0; j < 4; ++j)
                    acc[i][j] += av[i] * bv4[j];
        }
    }

#pragma unroll
    for (int i = 0; i < 4; ++i) {
        int gm = m0 + tmb + i;
        if (gm >= M) continue;
#pragma unroll
        for (int j = 0; j < 4; ++j) {
            int n = n0 + tnb + j;
            out[(size_t)gm * 768 + n] = acc[i][j] + bo[n];
        }
    }
}

extern "C" void kernel_launch(void* const* d_in, const int* in_sizes, int n_in,
                              void* d_out, int out_size, void* d_ws, size_t ws_size,
                              hipStream_t stream) {
    const float* x  = (const float*)d_in[0];
    const float* wq = (const float*)d_in[1];
    const float* bq = (const float*)d_in[2];
    const float* wk = (const float*)d_in[3];
    const float* bk = (const float*)d_in[4];
    const float* wv = (const float*)d_in[5];
    const float* bv = (const float*)d_in[6];
    const float* wo = (const float*)d_in[7];
    const float* bo = (const float*)d_in[8];
    const float* tp = (const float*)d_in[9];
    float* out = (float*)d_out;

    const size_t per = (size_t)BB * HH * LQ * DD;  // 12,595,200
    u16* qbuf = (u16*)d_ws;
    u16* kbuf = qbuf + per;
    u16* vbuf = kbuf + per;
    u16* obuf = vbuf + per;   // [B][L][H][D]

    dim3 g1(257, 12, 3);
    gemm_qkv<<<g1, 256, 0, stream>>>(x, wq, bq, wk, bk, wv, bv, qbuf, kbuf, vbuf);

    dim3 g2(17, BB * HH);
    attn_fused<<<g2, 256, 0, stream>>>(qbuf, kbuf, vbuf, tp, obuf);

    dim3 g3(257, 12);
    gemm_out<<<g3, 256, 0, stream>>>(obuf, wo, bo, out);
}

// Round 5
// 1397.892 us; speedup vs baseline: 4.6533x; 1.6731x over previous
//
#include <hip/hip_runtime.h>
#include <hip/hip_bf16.h>

#define BB 16
#define LQ 1025
#define FF 768
#define HH 12
#define DD 64
#define EPSF 1e-8f

typedef unsigned short u16;
typedef __attribute__((ext_vector_type(8))) short  bf16x8;
typedef __attribute__((ext_vector_type(4))) float  f32x4;

__device__ __forceinline__ float bf2f(u16 u) {
    union { unsigned int i; float f; } c;
    c.i = ((unsigned int)u) << 16;
    return c.f;
}

__device__ __forceinline__ u16 f2bf(float f) {
    union { float f; unsigned int i; } c;
    c.f = f;
    unsigned int x = c.i;
    unsigned int r = (x + 0x7fffu + ((x >> 16) & 1u)) >> 16;  // round-nearest-even
    return (u16)r;
}

// ---------------------------------------------------------------------------
// Kernel 1: fused QKV projection. fp32 inputs. (unchanged, passing)
// ---------------------------------------------------------------------------
__global__ __launch_bounds__(256) void gemm_qkv(
    const float* __restrict__ x,
    const float* __restrict__ wq, const float* __restrict__ bq,
    const float* __restrict__ wk, const float* __restrict__ bk,
    const float* __restrict__ wv, const float* __restrict__ bv,
    u16* __restrict__ qbuf, u16* __restrict__ kbuf, u16* __restrict__ vbuf)
{
    const int M = BB * LQ;  // 16400
    const int type = blockIdx.z;
    const float* __restrict__ w    = (type == 0) ? wq : (type == 1) ? wk : wv;
    const float* __restrict__ bias = (type == 0) ? bq : (type == 1) ? bk : bv;
    u16* __restrict__ outb         = (type == 0) ? qbuf : (type == 1) ? kbuf : vbuf;

    const int m0 = blockIdx.x * 64;
    const int h  = blockIdx.y;
    const int n0 = h * 64;

    __shared__ float As[16][64];
    __shared__ float Bs[16][64];

    const int t = threadIdx.x;
    const int am = t >> 2;
    const int ak = (t & 3) << 2;
    const int kb = t >> 4;
    const int nb = (t & 15) << 2;
    const int tmb = (t >> 4) << 2;
    const int tnb = (t & 15) << 2;

    float acc[4][4] = {{0.f}};

    for (int k0 = 0; k0 < 768; k0 += 16) {
        __syncthreads();
        {
            int gm = m0 + am;
            if (gm < M) {
                float4 u = *(const float4*)(x + (size_t)gm * 768 + k0 + ak);
                As[ak + 0][am] = u.x;
                As[ak + 1][am] = u.y;
                As[ak + 2][am] = u.z;
                As[ak + 3][am] = u.w;
            } else {
                As[ak + 0][am] = 0.f;
                As[ak + 1][am] = 0.f;
                As[ak + 2][am] = 0.f;
                As[ak + 3][am] = 0.f;
            }
        }
        {
            float4 u = *(const float4*)(w + (size_t)(k0 + kb) * 768 + n0 + nb);
            Bs[kb][nb + 0] = u.x;
            Bs[kb][nb + 1] = u.y;
            Bs[kb][nb + 2] = u.z;
            Bs[kb][nb + 3] = u.w;
        }
        __syncthreads();
#pragma unroll
        for (int kk = 0; kk < 16; ++kk) {
            float4 a4 = *(const float4*)&As[kk][tmb];
            float4 b4 = *(const float4*)&Bs[kk][tnb];
            float av[4] = {a4.x, a4.y, a4.z, a4.w};
            float bv4[4] = {b4.x, b4.y, b4.z, b4.w};
#pragma unroll
            for (int i = 0; i < 4; ++i)
#pragma unroll
                for (int j = 0; j < 4; ++j)
                    acc[i][j] += av[i] * bv4[j];
        }
    }

#pragma unroll
    for (int i = 0; i < 4; ++i) {
        int gm = m0 + tmb + i;
        if (gm >= M) continue;
        int b_idx = gm / LQ;
        int l     = gm - b_idx * LQ;
#pragma unroll
        for (int j = 0; j < 4; ++j) {
            int d = tnb + j;
            float v = acc[i][j] + bias[n0 + d];
            if (type == 0) v = fmaxf(v * 0.125f, 0.f) + EPSF;
            else if (type == 1) v = fmaxf(v, 0.f) + EPSF;
            outb[((size_t)(b_idx * HH + h) * LQ + l) * 64 + d] = f2bf(v);
        }
    }
}

// ---------------------------------------------------------------------------
// Kernel 2: fused attention on MFMA (16x16x32 bf16).
//   grid (17 q-tiles of 64, B*H), block 256 = 4 waves; wave w owns q-rows
//   [q0+16w, q0+16w+16).
//   LDS: SQ[64][72] bf16 (Q tile, then reused as S tile), Ks[64][72],
//   Vt[64][72] (V transposed: [d][key]).  Pitch 72 u16 = 144 B -> bank
//   stride 4 mod 32, row-strided frag reads are <=2-way (free).
//   Frag layouts (verified m89/m120): A[m=lane&15][k=quad*8+j],
//   B[k=quad*8+j][n=lane&15], C/D row=quad*4+reg, col=lane&15.
// ---------------------------------------------------------------------------
__global__ __launch_bounds__(256) void attn_fused(
    const u16* __restrict__ qbuf, const u16* __restrict__ kbuf,
    const u16* __restrict__ vbuf, const float* __restrict__ tp,
    u16* __restrict__ obuf)
{
    const int bh = blockIdx.y;          // b*H + h
    const int b  = bh / HH;
    const int h  = bh - b * HH;
    const int q0 = blockIdx.x * 64;

    __shared__ u16 SQ[64][72];   // Q tile, then S tile
    __shared__ u16 Ks[64][72];
    __shared__ u16 Vt[64][72];   // [d][key]

    const int t    = threadIdx.x;
    const int wave = t >> 6;            // 0..3
    const int lane = t & 63;
    const int quad = lane >> 4;         // 0..3
    const int l16  = lane & 15;
    const int w16  = wave << 4;

    const size_t base  = (size_t)bh * LQ * 64;
    const int    hbase = h * 4096;

    // ---- stage Q tile ----
    {
        const int row = t >> 2;          // 0..63
        const int s0  = (t & 3) << 4;    // 0,16,32,48
        const int qi = q0 + row;
        if (qi < LQ) {
            const uint4* qp = (const uint4*)(qbuf + base + (size_t)qi * 64 + s0);
            *(uint4*)&SQ[row][s0]     = qp[0];
            *(uint4*)&SQ[row][s0 + 8] = qp[1];
        } else {
            uint4 z; z.x = 0; z.y = 0; z.z = 0; z.w = 0;
            *(uint4*)&SQ[row][s0]     = z;
            *(uint4*)&SQ[row][s0 + 8] = z;
        }
    }
    __syncthreads();

    // ---- preload Q A-fragments (2 d-chunks of 32) ----
    bf16x8 qf0 = *(const bf16x8*)&SQ[w16 + l16][quad * 8];
    bf16x8 qf1 = *(const bf16x8*)&SQ[w16 + l16][32 + quad * 8];

    // per-(quad,reg) query metadata
    int  gqi_[4], gqj_[4];
    bool qv_[4], qc_[4];
#pragma unroll
    for (int reg = 0; reg < 4; ++reg) {
        int qi = q0 + w16 + quad * 4 + reg;
        qv_[reg] = (qi < LQ);
        qc_[reg] = (qi == 0);
        int qm1 = qi - 1;
        gqi_[reg] = (qv_[reg] && !qc_[reg]) ? (qm1 >> 5) : 0;
        gqj_[reg] = (qv_[reg] && !qc_[reg]) ? (qm1 & 31) : 0;
    }

    f32x4 acc_o[4];
#pragma unroll
    for (int dt = 0; dt < 4; ++dt) acc_o[dt] = (f32x4){0.f, 0.f, 0.f, 0.f};
    float den_acc[4] = {0.f, 0.f, 0.f, 0.f};

    for (int kt = 0; kt < 17; ++kt) {
        const int k0 = kt * 64;
        __syncthreads();   // prev PV done (Ss, Vt reads); Q-frags preloaded

        // ---- stage K (straight) and V (transposed) ----
        {
            const int row = t >> 2;          // key 0..63
            const int s0  = (t & 3) << 4;    // d seg
            const int ki = k0 + row;
            if (ki < LQ) {
                const uint4* kp = (const uint4*)(kbuf + base + (size_t)ki * 64 + s0);
                *(uint4*)&Ks[row][s0]     = kp[0];
                *(uint4*)&Ks[row][s0 + 8] = kp[1];
                const ushort4* vp = (const ushort4*)(vbuf + base + (size_t)ki * 64 + s0);
                ushort4 v0 = vp[0], v1 = vp[1], v2 = vp[2], v3 = vp[3];
                Vt[s0 +  0][row] = v0.x; Vt[s0 +  1][row] = v0.y;
                Vt[s0 +  2][row] = v0.z; Vt[s0 +  3][row] = v0.w;
                Vt[s0 +  4][row] = v1.x; Vt[s0 +  5][row] = v1.y;
                Vt[s0 +  6][row] = v1.z; Vt[s0 +  7][row] = v1.w;
                Vt[s0 +  8][row] = v2.x; Vt[s0 +  9][row] = v2.y;
                Vt[s0 + 10][row] = v2.z; Vt[s0 + 11][row] = v2.w;
                Vt[s0 + 12][row] = v3.x; Vt[s0 + 13][row] = v3.y;
                Vt[s0 + 14][row] = v3.z; Vt[s0 + 15][row] = v3.w;
            } else {
                uint4 z; z.x = 0; z.y = 0; z.z = 0; z.w = 0;
                *(uint4*)&Ks[row][s0]     = z;
                *(uint4*)&Ks[row][s0 + 8] = z;
#pragma unroll
                for (int j = 0; j < 16; ++j) Vt[s0 + j][row] = 0;
            }
        }
        __syncthreads();

        // ---- QK^T: 4 col-tiles of 16 keys, 2 MFMAs each ----
        f32x4 acc_s[4];
#pragma unroll
        for (int ct = 0; ct < 4; ++ct) {
            bf16x8 kf0 = *(const bf16x8*)&Ks[ct * 16 + l16][quad * 8];
            bf16x8 kf1 = *(const bf16x8*)&Ks[ct * 16 + l16][32 + quad * 8];
            f32x4 z = (f32x4){0.f, 0.f, 0.f, 0.f};
            z = __builtin_amdgcn_mfma_f32_16x16x32_bf16(qf0, kf0, z, 0, 0, 0);
            z = __builtin_amdgcn_mfma_f32_16x16x32_bf16(qf1, kf1, z, 0, 0, 0);
            acc_s[ct] = z;
        }

        // ---- mask + eps, accumulate den, write S (bf16) to SQ ----
#pragma unroll
        for (int ct = 0; ct < 4; ++ct) {
            int ki = k0 + ct * 16 + l16;
            bool kvalid = (ki < LQ);
            bool kcls   = (ki == 0);
            int gki = 0, gkj = 0;
            if (kvalid && !kcls) { gki = (ki - 1) >> 5; gkj = (ki - 1) & 31; }
#pragma unroll
            for (int reg = 0; reg < 4; ++reg) {
                float sv = 0.f;
                if (qv_[reg] && kvalid) {
                    float tm = 1.f;
                    if (!qc_[reg] && !kcls) {
                        int idx = ((gqi_[reg] - gki + 32) << 6) + (gqj_[reg] - gkj + 32);
                        tm = fabsf(tp[hbase + idx]);
                    }
                    sv = acc_s[ct][reg] * tm + EPSF;
                }
                den_acc[reg] += sv;
                SQ[w16 + quad * 4 + reg][ct * 16 + l16] = f2bf(sv);
            }
        }
        __syncthreads();

        // ---- PV: A = S (2 key-chunks), B = Vt (4 d-tiles) ----
        {
            bf16x8 a0 = *(const bf16x8*)&SQ[w16 + l16][quad * 8];
            bf16x8 a1 = *(const bf16x8*)&SQ[w16 + l16][32 + quad * 8];
#pragma unroll
            for (int dt = 0; dt < 4; ++dt) {
                bf16x8 b0 = *(const bf16x8*)&Vt[dt * 16 + l16][quad * 8];
                bf16x8 b1 = *(const bf16x8*)&Vt[dt * 16 + l16][32 + quad * 8];
                acc_o[dt] = __builtin_amdgcn_mfma_f32_16x16x32_bf16(a0, b0, acc_o[dt], 0, 0, 0);
                acc_o[dt] = __builtin_amdgcn_mfma_f32_16x16x32_bf16(a1, b1, acc_o[dt], 0, 0, 0);
            }
        }
    }

    // ---- reduce den across the 16 lanes of each quad-group ----
    float inv[4];
#pragma unroll
    for (int reg = 0; reg < 4; ++reg) {
        float r = den_acc[reg];
        r += __shfl_xor(r, 1);
        r += __shfl_xor(r, 2);
        r += __shfl_xor(r, 4);
        r += __shfl_xor(r, 8);
        inv[reg] = 1.f / r;
    }

    // ---- write O: obuf [B][L][H][D] bf16 ----
#pragma unroll
    for (int reg = 0; reg < 4; ++reg) {
        int qi = q0 + w16 + quad * 4 + reg;
        if (qi >= LQ) continue;
        u16* p = obuf + ((size_t)(b * LQ + qi) * HH + h) * 64;
#pragma unroll
        for (int dt = 0; dt < 4; ++dt)
            p[dt * 16 + l16] = f2bf(acc_o[dt][reg] * inv[reg]);
    }
}

// ---------------------------------------------------------------------------
// Kernel 3: output projection. (unchanged, passing)
// ---------------------------------------------------------------------------
__global__ __launch_bounds__(256) void gemm_out(
    const u16* __restrict__ a, const float* __restrict__ w,
    const float* __restrict__ bo, float* __restrict__ out)
{
    const int M = BB * LQ;
    const int m0 = blockIdx.x * 64;
    const int n0 = blockIdx.y * 64;

    __shared__ float As[16][64];
    __shared__ float Bs[16][64];

    const int t = threadIdx.x;
    const int am = t >> 2;
    const int ak = (t & 3) << 2;
    const int kb = t >> 4;
    const int nb = (t & 15) << 2;
    const int tmb = (t >> 4) << 2;
    const int tnb = (t & 15) << 2;

    float acc[4][4] = {{0.f}};

    for (int k0 = 0; k0 < 768; k0 += 16) {
        __syncthreads();
        {
            int gm = m0 + am;
            if (gm < M) {
                const u16* p = a + (size_t)gm * 768 + k0 + ak;
                ushort4 u = *(const ushort4*)p;
                As[ak + 0][am] = bf2f(u.x);
                As[ak + 1][am] = bf2f(u.y);
                As[ak + 2][am] = bf2f(u.z);
                As[ak + 3][am] = bf2f(u.w);
            } else {
                As[ak + 0][am] = 0.f; As[ak + 1][am] = 0.f;
                As[ak + 2][am] = 0.f; As[ak + 3][am] = 0.f;
            }
        }
        {
            float4 u = *(const float4*)(w + (size_t)(k0 + kb) * 768 + n0 + nb);
            Bs[kb][nb + 0] = u.x;
            Bs[kb][nb + 1] = u.y;
            Bs[kb][nb + 2] = u.z;
            Bs[kb][nb + 3] = u.w;
        }
        __syncthreads();
#pragma unroll
        for (int kk = 0; kk < 16; ++kk) {
            float4 a4 = *(const float4*)&As[kk][tmb];
            float4 b4 = *(const float4*)&Bs[kk][tnb];
            float av[4] = {a4.x, a4.y, a4.z, a4.w};
            float bv4[4] = {b4.x, b4.y, b4.z, b4.w};
#pragma unroll
            for (int i = 0; i < 4; ++i)
#pragma unroll
                for (int j = 0; j < 4; ++j)
                    acc[i][j] += av[i] * bv4[j];
        }
    }

#pragma unroll
    for (int i = 0; i < 4; ++i) {
        int gm = m0 + tmb + i;
        if (gm >= M) continue;
#pragma unroll
        for (int j = 0; j < 4; ++j) {
            int n = n0 + tnb + j;
            out[(size_t)gm * 768 + n] = acc[i][j] + bo[n];
        }
    }
}

extern "C" void kernel_launch(void* const* d_in, const int* in_sizes, int n_in,
                              void* d_out, int out_size, void* d_ws, size_t ws_size,
                              hipStream_t stream) {
    const float* x  = (const float*)d_in[0];
    const float* wq = (const float*)d_in[1];
    const float* bq = (const float*)d_in[2];
    const float* wk = (const float*)d_in[3];
    const float* bk = (const float*)d_in[4];
    const float* wv = (const float*)d_in[5];
    const float* bv = (const float*)d_in[6];
    const float* wo = (const float*)d_in[7];
    const float* bo = (const float*)d_in[8];
    const float* tp = (const float*)d_in[9];
    float* out = (float*)d_out;

    const size_t per = (size_t)BB * HH * LQ * DD;  // 12,595,200
    u16* qbuf = (u16*)d_ws;
    u16* kbuf = qbuf + per;
    u16* vbuf = kbuf + per;
    u16* obuf = vbuf + per;   // [B][L][H][D]

    dim3 g1(257, 12, 3);
    gemm_qkv<<<g1, 256, 0, stream>>>(x, wq, bq, wk, bk, wv, bv, qbuf, kbuf, vbuf);

    dim3 g2(17, BB * HH);
    attn_fused<<<g2, 256, 0, stream>>>(qbuf, kbuf, vbuf, tp, obuf);

    dim3 g3(257, 12);
    gemm_out<<<g3, 256, 0, stream>>>(obuf, wo, bo, out);
}

// Round 6
// 547.146 us; speedup vs baseline: 11.8885x; 2.5549x over previous
//
#include <hip/hip_runtime.h>
#include <hip/hip_bf16.h>

#define BB 16
#define LQ 1025
#define FF 768
#define HH 12
#define DD 64
#define EPSF 1e-8f

typedef unsigned short u16;
typedef __attribute__((ext_vector_type(8))) short  bf16x8;
typedef __attribute__((ext_vector_type(4))) float  f32x4;

__device__ __forceinline__ float bf2f(u16 u) {
    union { unsigned int i; float f; } c;
    c.i = ((unsigned int)u) << 16;
    return c.f;
}

__device__ __forceinline__ u16 f2bf(float f) {
    union { float f; unsigned int i; } c;
    c.f = f;
    unsigned int x = c.i;
    unsigned int r = (x + 0x7fffu + ((x >> 16) & 1u)) >> 16;  // round-nearest-even
    return (u16)r;
}

// ---------------------------------------------------------------------------
// Pre-pass A: convert x (fp32) -> xb (bf16), elementwise, grid-stride.
// ---------------------------------------------------------------------------
__global__ __launch_bounds__(256) void convert_x(
    const float* __restrict__ x, u16* __restrict__ xb, int n4)
{
    int i = blockIdx.x * blockDim.x + threadIdx.x;
    const int stride = gridDim.x * blockDim.x;
    for (; i < n4; i += stride) {
        float4 f = ((const float4*)x)[i];
        ushort4 o;
        o.x = f2bf(f.x); o.y = f2bf(f.y); o.z = f2bf(f.z); o.w = f2bf(f.w);
        ((ushort4*)xb)[i] = o;
    }
}

// ---------------------------------------------------------------------------
// Pre-pass B: transpose+convert the four 768x768 weight matrices to bf16.
//   src [r][c] fp32 -> dst [c][r] bf16.  64x64 tiles, LDS pitch 72 (16B rows).
// ---------------------------------------------------------------------------
__global__ __launch_bounds__(256) void transpose_w(
    const float* __restrict__ wq, const float* __restrict__ wk,
    const float* __restrict__ wv, const float* __restrict__ wo,
    u16* __restrict__ wqt, u16* __restrict__ wkt,
    u16* __restrict__ wvt, u16* __restrict__ wot)
{
    const int z = blockIdx.z;
    const float* __restrict__ src = (z == 0) ? wq : (z == 1) ? wk : (z == 2) ? wv : wo;
    u16* __restrict__ dst         = (z == 0) ? wqt : (z == 1) ? wkt : (z == 2) ? wvt : wot;

    const int c0 = blockIdx.x * 64;
    const int r0 = blockIdx.y * 64;

    __shared__ u16 tile[64][72];

    const int t   = threadIdx.x;
    const int row = t >> 2;          // 0..63
    const int cs  = (t & 3) << 4;    // 0,16,32,48

    // read 16 fp32 along c (coalesced), convert, store to LDS row
    {
        const float* p = src + (size_t)(r0 + row) * 768 + c0 + cs;
#pragma unroll
        for (int q = 0; q < 4; ++q) {
            float4 f = *(const float4*)(p + 4 * q);
            ushort4 o;
            o.x = f2bf(f.x); o.y = f2bf(f.y); o.z = f2bf(f.z); o.w = f2bf(f.w);
            *(ushort4*)&tile[row][cs + 4 * q] = o;
        }
    }
    __syncthreads();
    // write 16 bf16 along r (coalesced): dst[c0+row][r0+cs+j] = tile[cs+j][row]
    {
        u16* p = dst + (size_t)(c0 + row) * 768 + r0 + cs;
#pragma unroll
        for (int q = 0; q < 4; ++q) {
            ushort4 o;
            o.x = tile[cs + 4 * q + 0][row];
            o.y = tile[cs + 4 * q + 1][row];
            o.z = tile[cs + 4 * q + 2][row];
            o.w = tile[cs + 4 * q + 3][row];
            *(ushort4*)(p + 4 * q) = o;
        }
    }
}

// ---------------------------------------------------------------------------
// Kernel 1: fused QKV projection on MFMA.
//   A = xb [M][768] bf16; B = wqt/wkt/wvt [n=hd][k=f] bf16 (pre-transposed).
//   Block 256 = 4 waves, tile 128x64, BK=32; wave w owns m-rows [32w,32w+32).
//   A staged once per K-step, reused by 3 accumulator sets (q,k,v).
//   LDS pitch 40 u16 = 80 B: 16B-aligned rows, bank stride 20 (<=2-way, free).
//   Epilogue: +bias, q: relu(x/8)+eps, k: relu+eps; out [B][H][L][D] bf16.
// ---------------------------------------------------------------------------
__global__ __launch_bounds__(256) void gemm_qkv_mfma(
    const u16* __restrict__ xb,
    const u16* __restrict__ wqt, const u16* __restrict__ wkt,
    const u16* __restrict__ wvt,
    const float* __restrict__ bq, const float* __restrict__ bk,
    const float* __restrict__ bv,
    u16* __restrict__ qbuf, u16* __restrict__ kbuf, u16* __restrict__ vbuf)
{
    const int M  = BB * LQ;  // 16400
    const int m0 = blockIdx.x * 128;
    const int h  = blockIdx.y;
    const int n0 = h * 64;

    __shared__ u16 As[128][40];
    __shared__ u16 Bq[64][40];
    __shared__ u16 Bk[64][40];
    __shared__ u16 Bv[64][40];

    const int t    = threadIdx.x;
    const int wave = t >> 6;
    const int lane = t & 63;
    const int quad = lane >> 4;
    const int l16  = lane & 15;

    // staging indices
    const int sm   = t >> 1;          // 0..127 (A row)
    const int sseg = (t & 1) << 4;    // 0,16
    const int bn   = t >> 2;          // 0..63  (B row)
    const int bseg = (t & 3) << 3;    // 0,8,16,24

    f32x4 acc[3][2][4];
#pragma unroll
    for (int ty = 0; ty < 3; ++ty)
#pragma unroll
        for (int i = 0; i < 2; ++i)
#pragma unroll
            for (int j = 0; j < 4; ++j)
                acc[ty][i][j] = (f32x4){0.f, 0.f, 0.f, 0.f};

    for (int k0 = 0; k0 < 768; k0 += 32) {
        __syncthreads();
        // stage A (128x32 bf16)
        {
            int gm = m0 + sm;
            if (gm < M) {
                const uint4* p = (const uint4*)(xb + (size_t)gm * 768 + k0 + sseg);
                *(uint4*)&As[sm][sseg]     = p[0];
                *(uint4*)&As[sm][sseg + 8] = p[1];
            } else {
                uint4 z; z.x = 0; z.y = 0; z.z = 0; z.w = 0;
                *(uint4*)&As[sm][sseg]     = z;
                *(uint4*)&As[sm][sseg + 8] = z;
            }
        }
        // stage Bq/Bk/Bv (64x32 bf16 each)
        {
            size_t off = (size_t)(n0 + bn) * 768 + k0 + bseg;
            *(uint4*)&Bq[bn][bseg] = *(const uint4*)(wqt + off);
            *(uint4*)&Bk[bn][bseg] = *(const uint4*)(wkt + off);
            *(uint4*)&Bv[bn][bseg] = *(const uint4*)(wvt + off);
        }
        __syncthreads();

        bf16x8 af0 = *(const bf16x8*)&As[(wave << 5) + l16][quad * 8];
        bf16x8 af1 = *(const bf16x8*)&As[(wave << 5) + 16 + l16][quad * 8];
#pragma unroll
        for (int j = 0; j < 4; ++j) {
            bf16x8 bq8 = *(const bf16x8*)&Bq[16 * j + l16][quad * 8];
            acc[0][0][j] = __builtin_amdgcn_mfma_f32_16x16x32_bf16(af0, bq8, acc[0][0][j], 0, 0, 0);
            acc[0][1][j] = __builtin_amdgcn_mfma_f32_16x16x32_bf16(af1, bq8, acc[0][1][j], 0, 0, 0);
            bf16x8 bk8 = *(const bf16x8*)&Bk[16 * j + l16][quad * 8];
            acc[1][0][j] = __builtin_amdgcn_mfma_f32_16x16x32_bf16(af0, bk8, acc[1][0][j], 0, 0, 0);
            acc[1][1][j] = __builtin_amdgcn_mfma_f32_16x16x32_bf16(af1, bk8, acc[1][1][j], 0, 0, 0);
            bf16x8 bv8 = *(const bf16x8*)&Bv[16 * j + l16][quad * 8];
            acc[2][0][j] = __builtin_amdgcn_mfma_f32_16x16x32_bf16(af0, bv8, acc[2][0][j], 0, 0, 0);
            acc[2][1][j] = __builtin_amdgcn_mfma_f32_16x16x32_bf16(af1, bv8, acc[2][1][j], 0, 0, 0);
        }
    }

    // epilogue: C/D layout row=quad*4+reg, col=l16
#pragma unroll
    for (int i = 0; i < 2; ++i) {
#pragma unroll
        for (int reg = 0; reg < 4; ++reg) {
            int gm = m0 + (wave << 5) + (i << 4) + quad * 4 + reg;
            if (gm >= M) continue;
            int b_idx = gm / LQ;
            int l     = gm - b_idx * LQ;
            size_t obase = ((size_t)(b_idx * HH + h) * LQ + l) * 64;
#pragma unroll
            for (int j = 0; j < 4; ++j) {
                int d = 16 * j + l16;
                float fb = bq[n0 + d];
                float vq = acc[0][i][j][reg] + fb;
                vq = fmaxf(vq * 0.125f, 0.f) + EPSF;
                qbuf[obase + d] = f2bf(vq);
                float vk = acc[1][i][j][reg] + bk[n0 + d];
                vk = fmaxf(vk, 0.f) + EPSF;
                kbuf[obase + d] = f2bf(vk);
                float vv = acc[2][i][j][reg] + bv[n0 + d];
                vbuf[obase + d] = f2bf(vv);
            }
        }
    }
}

// ---------------------------------------------------------------------------
// Kernel 2: fused attention on MFMA (16x16x32 bf16).  (unchanged, passing)
// ---------------------------------------------------------------------------
__global__ __launch_bounds__(256) void attn_fused(
    const u16* __restrict__ qbuf, const u16* __restrict__ kbuf,
    const u16* __restrict__ vbuf, const float* __restrict__ tp,
    u16* __restrict__ obuf)
{
    const int bh = blockIdx.y;          // b*H + h
    const int b  = bh / HH;
    const int h  = bh - b * HH;
    const int q0 = blockIdx.x * 64;

    __shared__ u16 SQ[64][72];   // Q tile, then S tile
    __shared__ u16 Ks[64][72];
    __shared__ u16 Vt[64][72];   // [d][key]

    const int t    = threadIdx.x;
    const int wave = t >> 6;
    const int lane = t & 63;
    const int quad = lane >> 4;
    const int l16  = lane & 15;
    const int w16  = wave << 4;

    const size_t base  = (size_t)bh * LQ * 64;
    const int    hbase = h * 4096;

    {
        const int row = t >> 2;
        const int s0  = (t & 3) << 4;
        const int qi = q0 + row;
        if (qi < LQ) {
            const uint4* qp = (const uint4*)(qbuf + base + (size_t)qi * 64 + s0);
            *(uint4*)&SQ[row][s0]     = qp[0];
            *(uint4*)&SQ[row][s0 + 8] = qp[1];
        } else {
            uint4 z; z.x = 0; z.y = 0; z.z = 0; z.w = 0;
            *(uint4*)&SQ[row][s0]     = z;
            *(uint4*)&SQ[row][s0 + 8] = z;
        }
    }
    __syncthreads();

    bf16x8 qf0 = *(const bf16x8*)&SQ[w16 + l16][quad * 8];
    bf16x8 qf1 = *(const bf16x8*)&SQ[w16 + l16][32 + quad * 8];

    int  gqi_[4], gqj_[4];
    bool qv_[4], qc_[4];
#pragma unroll
    for (int reg = 0; reg < 4; ++reg) {
        int qi = q0 + w16 + quad * 4 + reg;
        qv_[reg] = (qi < LQ);
        qc_[reg] = (qi == 0);
        int qm1 = qi - 1;
        gqi_[reg] = (qv_[reg] && !qc_[reg]) ? (qm1 >> 5) : 0;
        gqj_[reg] = (qv_[reg] && !qc_[reg]) ? (qm1 & 31) : 0;
    }

    f32x4 acc_o[4];
#pragma unroll
    for (int dt = 0; dt < 4; ++dt) acc_o[dt] = (f32x4){0.f, 0.f, 0.f, 0.f};
    float den_acc[4] = {0.f, 0.f, 0.f, 0.f};

    for (int kt = 0; kt < 17; ++kt) {
        const int k0 = kt * 64;
        __syncthreads();

        {
            const int row = t >> 2;
            const int s0  = (t & 3) << 4;
            const int ki = k0 + row;
            if (ki < LQ) {
                const uint4* kp = (const uint4*)(kbuf + base + (size_t)ki * 64 + s0);
                *(uint4*)&Ks[row][s0]     = kp[0];
                *(uint4*)&Ks[row][s0 + 8] = kp[1];
                const ushort4* vp = (const ushort4*)(vbuf + base + (size_t)ki * 64 + s0);
                ushort4 v0 = vp[0], v1 = vp[1], v2 = vp[2], v3 = vp[3];
                Vt[s0 +  0][row] = v0.x; Vt[s0 +  1][row] = v0.y;
                Vt[s0 +  2][row] = v0.z; Vt[s0 +  3][row] = v0.w;
                Vt[s0 +  4][row] = v1.x; Vt[s0 +  5][row] = v1.y;
                Vt[s0 +  6][row] = v1.z; Vt[s0 +  7][row] = v1.w;
                Vt[s0 +  8][row] = v2.x; Vt[s0 +  9][row] = v2.y;
                Vt[s0 + 10][row] = v2.z; Vt[s0 + 11][row] = v2.w;
                Vt[s0 + 12][row] = v3.x; Vt[s0 + 13][row] = v3.y;
                Vt[s0 + 14][row] = v3.z; Vt[s0 + 15][row] = v3.w;
            } else {
                uint4 z; z.x = 0; z.y = 0; z.z = 0; z.w = 0;
                *(uint4*)&Ks[row][s0]     = z;
                *(uint4*)&Ks[row][s0 + 8] = z;
#pragma unroll
                for (int j = 0; j < 16; ++j) Vt[s0 + j][row] = 0;
            }
        }
        __syncthreads();

        f32x4 acc_s[4];
#pragma unroll
        for (int ct = 0; ct < 4; ++ct) {
            bf16x8 kf0 = *(const bf16x8*)&Ks[ct * 16 + l16][quad * 8];
            bf16x8 kf1 = *(const bf16x8*)&Ks[ct * 16 + l16][32 + quad * 8];
            f32x4 z = (f32x4){0.f, 0.f, 0.f, 0.f};
            z = __builtin_amdgcn_mfma_f32_16x16x32_bf16(qf0, kf0, z, 0, 0, 0);
            z = __builtin_amdgcn_mfma_f32_16x16x32_bf16(qf1, kf1, z, 0, 0, 0);
            acc_s[ct] = z;
        }

#pragma unroll
        for (int ct = 0; ct < 4; ++ct) {
            int ki = k0 + ct * 16 + l16;
            bool kvalid = (ki < LQ);
            bool kcls   = (ki == 0);
            int gki = 0, gkj = 0;
            if (kvalid && !kcls) { gki = (ki - 1) >> 5; gkj = (ki - 1) & 31; }
#pragma unroll
            for (int reg = 0; reg < 4; ++reg) {
                float sv = 0.f;
                if (qv_[reg] && kvalid) {
                    float tm = 1.f;
                    if (!qc_[reg] && !kcls) {
                        int idx = ((gqi_[reg] - gki + 32) << 6) + (gqj_[reg] - gkj + 32);
                        tm = fabsf(tp[hbase + idx]);
                    }
                    sv = acc_s[ct][reg] * tm + EPSF;
                }
                den_acc[reg] += sv;
                SQ[w16 + quad * 4 + reg][ct * 16 + l16] = f2bf(sv);
            }
        }
        __syncthreads();

        {
            bf16x8 a0 = *(const bf16x8*)&SQ[w16 + l16][quad * 8];
            bf16x8 a1 = *(const bf16x8*)&SQ[w16 + l16][32 + quad * 8];
#pragma unroll
            for (int dt = 0; dt < 4; ++dt) {
                bf16x8 b0 = *(const bf16x8*)&Vt[dt * 16 + l16][quad * 8];
                bf16x8 b1 = *(const bf16x8*)&Vt[dt * 16 + l16][32 + quad * 8];
                acc_o[dt] = __builtin_amdgcn_mfma_f32_16x16x32_bf16(a0, b0, acc_o[dt], 0, 0, 0);
                acc_o[dt] = __builtin_amdgcn_mfma_f32_16x16x32_bf16(a1, b1, acc_o[dt], 0, 0, 0);
            }
        }
    }

    float inv[4];
#pragma unroll
    for (int reg = 0; reg < 4; ++reg) {
        float r = den_acc[reg];
        r += __shfl_xor(r, 1);
        r += __shfl_xor(r, 2);
        r += __shfl_xor(r, 4);
        r += __shfl_xor(r, 8);
        inv[reg] = 1.f / r;
    }

#pragma unroll
    for (int reg = 0; reg < 4; ++reg) {
        int qi = q0 + w16 + quad * 4 + reg;
        if (qi >= LQ) continue;
        u16* p = obuf + ((size_t)(b * LQ + qi) * HH + h) * 64;
#pragma unroll
        for (int dt = 0; dt < 4; ++dt)
            p[dt * 16 + l16] = f2bf(acc_o[dt][reg] * inv[reg]);
    }
}

// ---------------------------------------------------------------------------
// Kernel 3: output projection on MFMA.
//   A = obuf [M][768] bf16; B = wot [n=f][k=hd] bf16 (pre-transposed).
//   Same tiling as gemm_qkv_mfma, single type; out fp32 + bo.
// ---------------------------------------------------------------------------
__global__ __launch_bounds__(256) void gemm_out_mfma(
    const u16* __restrict__ a, const u16* __restrict__ wot,
    const float* __restrict__ bo, float* __restrict__ out)
{
    const int M  = BB * LQ;
    const int m0 = blockIdx.x * 128;
    const int n0 = blockIdx.y * 64;

    __shared__ u16 As[128][40];
    __shared__ u16 Bs[64][40];

    const int t    = threadIdx.x;
    const int wave = t >> 6;
    const int lane = t & 63;
    const int quad = lane >> 4;
    const int l16  = lane & 15;

    const int sm   = t >> 1;
    const int sseg = (t & 1) << 4;
    const int bn   = t >> 2;
    const int bseg = (t & 3) << 3;

    f32x4 acc[2][4];
#pragma unroll
    for (int i = 0; i < 2; ++i)
#pragma unroll
        for (int j = 0; j < 4; ++j)
            acc[i][j] = (f32x4){0.f, 0.f, 0.f, 0.f};

    for (int k0 = 0; k0 < 768; k0 += 32) {
        __syncthreads();
        {
            int gm = m0 + sm;
            if (gm < M) {
                const uint4* p = (const uint4*)(a + (size_t)gm * 768 + k0 + sseg);
                *(uint4*)&As[sm][sseg]     = p[0];
                *(uint4*)&As[sm][sseg + 8] = p[1];
            } else {
                uint4 z; z.x = 0; z.y = 0; z.z = 0; z.w = 0;
                *(uint4*)&As[sm][sseg]     = z;
                *(uint4*)&As[sm][sseg + 8] = z;
            }
        }
        {
            *(uint4*)&Bs[bn][bseg] =
                *(const uint4*)(wot + (size_t)(n0 + bn) * 768 + k0 + bseg);
        }
        __syncthreads();

        bf16x8 af0 = *(const bf16x8*)&As[(wave << 5) + l16][quad * 8];
        bf16x8 af1 = *(const bf16x8*)&As[(wave << 5) + 16 + l16][quad * 8];
#pragma unroll
        for (int j = 0; j < 4; ++j) {
            bf16x8 b8 = *(const bf16x8*)&Bs[16 * j + l16][quad * 8];
            acc[0][j] = __builtin_amdgcn_mfma_f32_16x16x32_bf16(af0, b8, acc[0][j], 0, 0, 0);
            acc[1][j] = __builtin_amdgcn_mfma_f32_16x16x32_bf16(af1, b8, acc[1][j], 0, 0, 0);
        }
    }

#pragma unroll
    for (int i = 0; i < 2; ++i) {
#pragma unroll
        for (int reg = 0; reg < 4; ++reg) {
            int gm = m0 + (wave << 5) + (i << 4) + quad * 4 + reg;
            if (gm >= M) continue;
            float* p = out + (size_t)gm * 768;
#pragma unroll
            for (int j = 0; j < 4; ++j) {
                int n = n0 + 16 * j + l16;
                p[n] = acc[i][j][reg] + bo[n];
            }
        }
    }
}

extern "C" void kernel_launch(void* const* d_in, const int* in_sizes, int n_in,
                              void* d_out, int out_size, void* d_ws, size_t ws_size,
                              hipStream_t stream) {
    const float* x  = (const float*)d_in[0];
    const float* wq = (const float*)d_in[1];
    const float* bq = (const float*)d_in[2];
    const float* wk = (const float*)d_in[3];
    const float* bk = (const float*)d_in[4];
    const float* wv = (const float*)d_in[5];
    const float* bv = (const float*)d_in[6];
    const float* wo = (const float*)d_in[7];
    const float* bo = (const float*)d_in[8];
    const float* tp = (const float*)d_in[9];
    float* out = (float*)d_out;

    const size_t per = (size_t)BB * HH * LQ * DD;  // 12,595,200 elements
    const size_t wsz = (size_t)FF * FF;            // 589,824 elements
    u16* qbuf = (u16*)d_ws;
    u16* kbuf = qbuf + per;
    u16* vbuf = kbuf + per;
    u16* xobuf = vbuf + per;     // xb during QKV GEMM, obuf afterwards
    u16* wqt  = xobuf + per;
    u16* wkt  = wqt + wsz;
    u16* wvt  = wkt + wsz;
    u16* wot  = wvt + wsz;

    // pre-pass: convert + transpose
    convert_x<<<2048, 256, 0, stream>>>(x, xobuf, (int)(per / 4));
    dim3 gt(12, 12, 4);
    transpose_w<<<gt, 256, 0, stream>>>(wq, wk, wv, wo, wqt, wkt, wvt, wot);

    dim3 g1(129, 12);
    gemm_qkv_mfma<<<g1, 256, 0, stream>>>(xobuf, wqt, wkt, wvt, bq, bk, bv,
                                          qbuf, kbuf, vbuf);

    dim3 g2(17, BB * HH);
    attn_fused<<<g2, 256, 0, stream>>>(qbuf, kbuf, vbuf, tp, xobuf);

    dim3 g3(129, 12);
    gemm_out_mfma<<<g3, 256, 0, stream>>>(xobuf, wot, bo, out);
}

// Round 7
// 484.791 us; speedup vs baseline: 13.4176x; 1.1286x over previous
//
#include <hip/hip_runtime.h>
#include <hip/hip_bf16.h>

#define BB 16
#define LQ 1025
#define FF 768
#define HH 12
#define DD 64
#define EPSF 1e-8f

#define TPSTRIDE 6400     // per-head mask table: [0,64)=0, [64,4160)=|tp|, [4160,6400)=1
#define QPART_CLS 6270    // CLS-query qpart -> all reads land in the ones band
#define VSTRIDE 1040      // vtbuf key stride (16B aligned, >=1025, zero-padded)

typedef unsigned short u16;
typedef __attribute__((ext_vector_type(8))) short  bf16x8;
typedef __attribute__((ext_vector_type(4))) float  f32x4;

__device__ __forceinline__ float bf2f(u16 u) {
    union { unsigned int i; float f; } c;
    c.i = ((unsigned int)u) << 16;
    return c.f;
}

__device__ __forceinline__ u16 f2bf(float f) {
    union { float f; unsigned int i; } c;
    c.f = f;
    unsigned int x = c.i;
    unsigned int r = (x + 0x7fffu + ((x >> 16) & 1u)) >> 16;  // round-nearest-even
    return (u16)r;
}

// ---------------------------------------------------------------------------
// Pre-pass A: convert x (fp32) -> xb (bf16).
// ---------------------------------------------------------------------------
__global__ __launch_bounds__(256) void convert_x(
    const float* __restrict__ x, u16* __restrict__ xb, int n4)
{
    int i = blockIdx.x * blockDim.x + threadIdx.x;
    const int stride = gridDim.x * blockDim.x;
    for (; i < n4; i += stride) {
        float4 f = ((const float4*)x)[i];
        ushort4 o;
        o.x = f2bf(f.x); o.y = f2bf(f.y); o.z = f2bf(f.z); o.w = f2bf(f.w);
        ((ushort4*)xb)[i] = o;
    }
}

// ---------------------------------------------------------------------------
// Pre-pass B: transpose+convert the four 768x768 weight matrices to bf16.
// ---------------------------------------------------------------------------
__global__ __launch_bounds__(256) void transpose_w(
    const float* __restrict__ wq, const float* __restrict__ wk,
    const float* __restrict__ wv, const float* __restrict__ wo,
    u16* __restrict__ wqt, u16* __restrict__ wkt,
    u16* __restrict__ wvt, u16* __restrict__ wot)
{
    const int z = blockIdx.z;
    const float* __restrict__ src = (z == 0) ? wq : (z == 1) ? wk : (z == 2) ? wv : wo;
    u16* __restrict__ dst         = (z == 0) ? wqt : (z == 1) ? wkt : (z == 2) ? wvt : wot;

    const int c0 = blockIdx.x * 64;
    const int r0 = blockIdx.y * 64;

    __shared__ u16 tile[64][72];

    const int t   = threadIdx.x;
    const int row = t >> 2;
    const int cs  = (t & 3) << 4;

    {
        const float* p = src + (size_t)(r0 + row) * 768 + c0 + cs;
#pragma unroll
        for (int q = 0; q < 4; ++q) {
            float4 f = *(const float4*)(p + 4 * q);
            ushort4 o;
            o.x = f2bf(f.x); o.y = f2bf(f.y); o.z = f2bf(f.z); o.w = f2bf(f.w);
            *(ushort4*)&tile[row][cs + 4 * q] = o;
        }
    }
    __syncthreads();
    {
        u16* p = dst + (size_t)(c0 + row) * 768 + r0 + cs;
#pragma unroll
        for (int q = 0; q < 4; ++q) {
            ushort4 o;
            o.x = tile[cs + 4 * q + 0][row];
            o.y = tile[cs + 4 * q + 1][row];
            o.z = tile[cs + 4 * q + 2][row];
            o.w = tile[cs + 4 * q + 3][row];
            *(ushort4*)(p + 4 * q) = o;
        }
    }
}

// ---------------------------------------------------------------------------
// Pre-pass C: build per-head mask table tpa[h][TPSTRIDE]:
//   [0,64)=0 (guard for invalid keys), [64,4160)=|tp[h]|, [4160,TPSTRIDE)=1.
// ---------------------------------------------------------------------------
__global__ __launch_bounds__(256) void build_tpa(
    const float* __restrict__ tp, float* __restrict__ tpa)
{
    int i = blockIdx.x * 256 + threadIdx.x;
    if (i >= HH * TPSTRIDE) return;
    int h = i / TPSTRIDE, j = i - h * TPSTRIDE;
    float v;
    if (j < 64) v = 0.f;
    else if (j < 64 + 4096) v = fabsf(tp[h * 4096 + (j - 64)]);
    else v = 1.f;
    tpa[i] = v;
}

// ---------------------------------------------------------------------------
// Pre-pass D: transpose V per (b,h): vbuf [bh][l][d] -> vtbuf [bh][d][VSTRIDE]
//   (keys zero-padded to VSTRIDE so attention staging needs no guards).
//   LDS pitch 65 (odd) keeps both scalar phases ~conflict-free.
// ---------------------------------------------------------------------------
__global__ __launch_bounds__(256) void transpose_v(
    const u16* __restrict__ vbuf, u16* __restrict__ vtbuf)
{
    const int bh = blockIdx.y;
    const int lt = blockIdx.x;           // 0..16
    __shared__ u16 tile[64][65];
    const int t   = threadIdx.x;
    const int row = t >> 2;              // 0..63
    const int seg = (t & 3) << 4;        // 0,16,32,48

    {
        int l = lt * 64 + row;
        if (l < LQ) {
            const ushort4* p = (const ushort4*)(vbuf + ((size_t)bh * LQ + l) * 64 + seg);
#pragma unroll
            for (int q = 0; q < 4; ++q) {
                ushort4 a = p[q];
                tile[row][seg + 4 * q + 0] = a.x;
                tile[row][seg + 4 * q + 1] = a.y;
                tile[row][seg + 4 * q + 2] = a.z;
                tile[row][seg + 4 * q + 3] = a.w;
            }
        } else {
#pragma unroll
            for (int j = 0; j < 16; ++j) tile[row][seg + j] = 0;
        }
    }
    __syncthreads();
    {
        int kbase = lt * 64 + seg;
        if (kbase + 16 <= VSTRIDE) {
            u16* q = vtbuf + (size_t)bh * 64 * VSTRIDE + (size_t)row * VSTRIDE + kbase;
#pragma unroll
            for (int g = 0; g < 4; ++g) {
                ushort4 o;
                o.x = tile[seg + 4 * g + 0][row];
                o.y = tile[seg + 4 * g + 1][row];
                o.z = tile[seg + 4 * g + 2][row];
                o.w = tile[seg + 4 * g + 3][row];
                *(ushort4*)(q + 4 * g) = o;
            }
        }
    }
}

// ---------------------------------------------------------------------------
// Kernel 1: fused QKV projection on MFMA. (unchanged, passing)
// ---------------------------------------------------------------------------
__global__ __launch_bounds__(256) void gemm_qkv_mfma(
    const u16* __restrict__ xb,
    const u16* __restrict__ wqt, const u16* __restrict__ wkt,
    const u16* __restrict__ wvt,
    const float* __restrict__ bq, const float* __restrict__ bk,
    const float* __restrict__ bv,
    u16* __restrict__ qbuf, u16* __restrict__ kbuf, u16* __restrict__ vbuf)
{
    const int M  = BB * LQ;
    const int m0 = blockIdx.x * 128;
    const int h  = blockIdx.y;
    const int n0 = h * 64;

    __shared__ u16 As[128][40];
    __shared__ u16 Bq[64][40];
    __shared__ u16 Bk[64][40];
    __shared__ u16 Bv[64][40];

    const int t    = threadIdx.x;
    const int wave = t >> 6;
    const int lane = t & 63;
    const int quad = lane >> 4;
    const int l16  = lane & 15;

    const int sm   = t >> 1;
    const int sseg = (t & 1) << 4;
    const int bn   = t >> 2;
    const int bseg = (t & 3) << 3;

    f32x4 acc[3][2][4];
#pragma unroll
    for (int ty = 0; ty < 3; ++ty)
#pragma unroll
        for (int i = 0; i < 2; ++i)
#pragma unroll
            for (int j = 0; j < 4; ++j)
                acc[ty][i][j] = (f32x4){0.f, 0.f, 0.f, 0.f};

    for (int k0 = 0; k0 < 768; k0 += 32) {
        __syncthreads();
        {
            int gm = m0 + sm;
            if (gm < M) {
                const uint4* p = (const uint4*)(xb + (size_t)gm * 768 + k0 + sseg);
                *(uint4*)&As[sm][sseg]     = p[0];
                *(uint4*)&As[sm][sseg + 8] = p[1];
            } else {
                uint4 z; z.x = 0; z.y = 0; z.z = 0; z.w = 0;
                *(uint4*)&As[sm][sseg]     = z;
                *(uint4*)&As[sm][sseg + 8] = z;
            }
        }
        {
            size_t off = (size_t)(n0 + bn) * 768 + k0 + bseg;
            *(uint4*)&Bq[bn][bseg] = *(const uint4*)(wqt + off);
            *(uint4*)&Bk[bn][bseg] = *(const uint4*)(wkt + off);
            *(uint4*)&Bv[bn][bseg] = *(const uint4*)(wvt + off);
        }
        __syncthreads();

        bf16x8 af0 = *(const bf16x8*)&As[(wave << 5) + l16][quad * 8];
        bf16x8 af1 = *(const bf16x8*)&As[(wave << 5) + 16 + l16][quad * 8];
#pragma unroll
        for (int j = 0; j < 4; ++j) {
            bf16x8 bq8 = *(const bf16x8*)&Bq[16 * j + l16][quad * 8];
            acc[0][0][j] = __builtin_amdgcn_mfma_f32_16x16x32_bf16(af0, bq8, acc[0][0][j], 0, 0, 0);
            acc[0][1][j] = __builtin_amdgcn_mfma_f32_16x16x32_bf16(af1, bq8, acc[0][1][j], 0, 0, 0);
            bf16x8 bk8 = *(const bf16x8*)&Bk[16 * j + l16][quad * 8];
            acc[1][0][j] = __builtin_amdgcn_mfma_f32_16x16x32_bf16(af0, bk8, acc[1][0][j], 0, 0, 0);
            acc[1][1][j] = __builtin_amdgcn_mfma_f32_16x16x32_bf16(af1, bk8, acc[1][1][j], 0, 0, 0);
            bf16x8 bv8 = *(const bf16x8*)&Bv[16 * j + l16][quad * 8];
            acc[2][0][j] = __builtin_amdgcn_mfma_f32_16x16x32_bf16(af0, bv8, acc[2][0][j], 0, 0, 0);
            acc[2][1][j] = __builtin_amdgcn_mfma_f32_16x16x32_bf16(af1, bv8, acc[2][1][j], 0, 0, 0);
        }
    }

#pragma unroll
    for (int i = 0; i < 2; ++i) {
#pragma unroll
        for (int reg = 0; reg < 4; ++reg) {
            int gm = m0 + (wave << 5) + (i << 4) + quad * 4 + reg;
            if (gm >= M) continue;
            int b_idx = gm / LQ;
            int l     = gm - b_idx * LQ;
            size_t obase = ((size_t)(b_idx * HH + h) * LQ + l) * 64;
#pragma unroll
            for (int j = 0; j < 4; ++j) {
                int d = 16 * j + l16;
                float vq = acc[0][i][j][reg] + bq[n0 + d];
                vq = fmaxf(vq * 0.125f, 0.f) + EPSF;
                qbuf[obase + d] = f2bf(vq);
                float vk = acc[1][i][j][reg] + bk[n0 + d];
                vk = fmaxf(vk, 0.f) + EPSF;
                kbuf[obase + d] = f2bf(vk);
                float vv = acc[2][i][j][reg] + bv[n0 + d];
                vbuf[obase + d] = f2bf(vv);
            }
        }
    }
}

// ---------------------------------------------------------------------------
// Kernel 2: fused attention, v3.
//   S^T = K.Q^T MFMA (per-lane q = w16+l16), table-driven mask with idx
//   ladder (-128/k-tile), register prefetch of next K/V tile, pre-transposed
//   V (vtbuf). 3 barriers/tile.
// ---------------------------------------------------------------------------
__global__ __launch_bounds__(256) void attn_fused(
    const u16* __restrict__ qbuf, const u16* __restrict__ kbuf,
    const u16* __restrict__ vtbuf, const float* __restrict__ tpa,
    u16* __restrict__ obuf)
{
    const int bh = blockIdx.y;
    const int b  = bh / HH;
    const int h  = bh - b * HH;
    const int q0 = blockIdx.x * 64;

    __shared__ u16 SQ[64][72];   // Q tile, then S tile (each wave owns rows w16..w16+15)
    __shared__ u16 Ks[64][72];
    __shared__ u16 Vt[64][72];   // [d][key]

    const int t    = threadIdx.x;
    const int wave = t >> 6;
    const int lane = t & 63;
    const int quad = lane >> 4;
    const int l16  = lane & 15;
    const int w16  = wave << 4;

    const size_t base  = (size_t)bh * LQ * 64;
    const size_t vbase = (size_t)bh * 64 * VSTRIDE;
    const float* tb = tpa + h * TPSTRIDE;

    const int srow = t >> 2;          // staging row
    const int sseg = (t & 3) << 4;    // staging seg (u16)

    // ---- stage Q tile (unconditional; overrun reads land in kbuf, harmless) ----
    {
        const uint4* qp = (const uint4*)(qbuf + base + (size_t)(q0 + srow) * 64 + sseg);
        *(uint4*)&SQ[srow][sseg]     = qp[0];
        *(uint4*)&SQ[srow][sseg + 8] = qp[1];
    }

    // ---- per-lane q metadata (single q row per lane) ----
    const int qi = q0 + w16 + l16;
    int qpart;
    if (qi == 0) qpart = QPART_CLS;
    else { int qm1 = qi - 1; qpart = (((qm1 >> 5) + 32) << 6) + (qm1 & 31) + 32; }

    // mask-table index ladder: idx[e] for key = ct*16+quad*4+reg at kt=0;
    // idx -= 128 per k-tile. Signed shifts make the CLS-key (km1=-1)
    // trajectory correct for kt>=1; kt==0 value is overridden below.
    int idx[16];
#pragma unroll
    for (int ct = 0; ct < 4; ++ct)
#pragma unroll
        for (int reg = 0; reg < 4; ++reg) {
            int km1 = ct * 16 + quad * 4 + reg - 1;
            idx[ct * 4 + reg] = 64 + qpart - (((km1 >> 5) << 6) + (km1 & 31));
        }

    // ---- prefetch K/V tile 0 into registers ----
    uint4 kr0, kr1, vr0, vr1;
    {
        uint4 z; z.x = 0; z.y = 0; z.z = 0; z.w = 0;
        int ki = srow;                      // k0 = 0
        if (ki < LQ) {
            const uint4* kp = (const uint4*)(kbuf + base + (size_t)ki * 64 + sseg);
            kr0 = kp[0]; kr1 = kp[1];
        } else { kr0 = z; kr1 = z; }
        const uint4* vp = (const uint4*)(vtbuf + vbase + (size_t)srow * VSTRIDE + sseg);
        vr0 = vp[0]; vr1 = vp[1];
    }

    __syncthreads();   // Q staged

    // ---- preload Q B-fragments ----
    bf16x8 qf0 = *(const bf16x8*)&SQ[w16 + l16][quad * 8];
    bf16x8 qf1 = *(const bf16x8*)&SQ[w16 + l16][32 + quad * 8];

    f32x4 acc_o[4];
#pragma unroll
    for (int dt = 0; dt < 4; ++dt) acc_o[dt] = (f32x4){0.f, 0.f, 0.f, 0.f};
    float den = 0.f;

    for (int kt = 0; kt < 17; ++kt) {
        __syncthreads();   // prev PV done reading Ks/Vt; qf loaded (kt=0)

        // write prefetched K/V into LDS
        *(uint4*)&Ks[srow][sseg]     = kr0;
        *(uint4*)&Ks[srow][sseg + 8] = kr1;
        *(uint4*)&Vt[srow][sseg]     = vr0;
        *(uint4*)&Vt[srow][sseg + 8] = vr1;

        // issue tm loads (independent of scores -> overlap with QK MFMAs)
        float tmv[16];
#pragma unroll
        for (int e = 0; e < 16; ++e) tmv[e] = tb[idx[e]];

        // prefetch next K/V tile
        if (kt < 16) {
            uint4 z; z.x = 0; z.y = 0; z.z = 0; z.w = 0;
            int k0n = (kt + 1) * 64;
            int ki = k0n + srow;
            if (ki < LQ) {
                const uint4* kp = (const uint4*)(kbuf + base + (size_t)ki * 64 + sseg);
                kr0 = kp[0]; kr1 = kp[1];
            } else { kr0 = z; kr1 = z; }
            int vcol = k0n + sseg;
            if (vcol + 16 <= VSTRIDE) {
                const uint4* vp = (const uint4*)(vtbuf + vbase + (size_t)srow * VSTRIDE + vcol);
                vr0 = vp[0]; vr1 = vp[1];
            } else { vr0 = z; vr1 = z; }
        }

        __syncthreads();   // staging visible

        // ---- QK^T as S^T = K.Q^T ----
        f32x4 acc_s[4];
#pragma unroll
        for (int ct = 0; ct < 4; ++ct) {
            bf16x8 kf0 = *(const bf16x8*)&Ks[ct * 16 + l16][quad * 8];
            bf16x8 kf1 = *(const bf16x8*)&Ks[ct * 16 + l16][32 + quad * 8];
            f32x4 z = (f32x4){0.f, 0.f, 0.f, 0.f};
            z = __builtin_amdgcn_mfma_f32_16x16x32_bf16(kf0, qf0, z, 0, 0, 0);
            z = __builtin_amdgcn_mfma_f32_16x16x32_bf16(kf1, qf1, z, 0, 0, 0);
            acc_s[ct] = z;
        }

        // CLS key (k==0) exists only at kt==0, element (ct=0,reg=0) of quad==0
        if (kt == 0) { if (quad == 0) tmv[0] = 1.0f; }

        // ---- mask + eps + den + S write (4 x b64, own row) ----
#pragma unroll
        for (int ct = 0; ct < 4; ++ct) {
            float s0 = acc_s[ct][0] * tmv[ct * 4 + 0] + EPSF;
            float s1 = acc_s[ct][1] * tmv[ct * 4 + 1] + EPSF;
            float s2 = acc_s[ct][2] * tmv[ct * 4 + 2] + EPSF;
            float s3 = acc_s[ct][3] * tmv[ct * 4 + 3] + EPSF;
            den += (s0 + s1) + (s2 + s3);
            ushort4 w;
            w.x = f2bf(s0); w.y = f2bf(s1); w.z = f2bf(s2); w.w = f2bf(s3);
            *(ushort4*)&SQ[w16 + l16][ct * 16 + quad * 4] = w;
        }
#pragma unroll
        for (int e = 0; e < 16; ++e) idx[e] -= 128;

        __syncthreads();   // S visible (intra-wave dep; barrier for safety)

        // ---- PV: A = S (own row), B = Vt ----
        {
            bf16x8 a0 = *(const bf16x8*)&SQ[w16 + l16][quad * 8];
            bf16x8 a1 = *(const bf16x8*)&SQ[w16 + l16][32 + quad * 8];
#pragma unroll
            for (int dt = 0; dt < 4; ++dt) {
                bf16x8 b0 = *(const bf16x8*)&Vt[dt * 16 + l16][quad * 8];
                bf16x8 b1 = *(const bf16x8*)&Vt[dt * 16 + l16][32 + quad * 8];
                acc_o[dt] = __builtin_amdgcn_mfma_f32_16x16x32_bf16(a0, b0, acc_o[dt], 0, 0, 0);
                acc_o[dt] = __builtin_amdgcn_mfma_f32_16x16x32_bf16(a1, b1, acc_o[dt], 0, 0, 0);
            }
        }
    }

    // ---- den: sum across quads (keys split by quad), per-lane q = w16+l16 ----
    den += __shfl_xor(den, 16);
    den += __shfl_xor(den, 32);
    float invd = 1.f / den;

    // ---- write O: C row = quad*4+reg needs inv(q=w16+row) from lane row ----
#pragma unroll
    for (int reg = 0; reg < 4; ++reg) {
        int r = quad * 4 + reg;
        float iv = __shfl(invd, r, 64);
        int qrow = q0 + w16 + r;
        if (qrow < LQ) {
            u16* p = obuf + ((size_t)(b * LQ + qrow) * HH + h) * 64;
#pragma unroll
            for (int dt = 0; dt < 4; ++dt)
                p[dt * 16 + l16] = f2bf(acc_o[dt][reg] * iv);
        }
    }
}

// ---------------------------------------------------------------------------
// Kernel 3: output projection on MFMA. (unchanged, passing)
// ---------------------------------------------------------------------------
__global__ __launch_bounds__(256) void gemm_out_mfma(
    const u16* __restrict__ a, const u16* __restrict__ wot,
    const float* __restrict__ bo, float* __restrict__ out)
{
    const int M  = BB * LQ;
    const int m0 = blockIdx.x * 128;
    const int n0 = blockIdx.y * 64;

    __shared__ u16 As[128][40];
    __shared__ u16 Bs[64][40];

    const int t    = threadIdx.x;
    const int wave = t >> 6;
    const int lane = t & 63;
    const int quad = lane >> 4;
    const int l16  = lane & 15;

    const int sm   = t >> 1;
    const int sseg = (t & 1) << 4;
    const int bn   = t >> 2;
    const int bseg = (t & 3) << 3;

    f32x4 acc[2][4];
#pragma unroll
    for (int i = 0; i < 2; ++i)
#pragma unroll
        for (int j = 0; j < 4; ++j)
            acc[i][j] = (f32x4){0.f, 0.f, 0.f, 0.f};

    for (int k0 = 0; k0 < 768; k0 += 32) {
        __syncthreads();
        {
            int gm = m0 + sm;
            if (gm < M) {
                const uint4* p = (const uint4*)(a + (size_t)gm * 768 + k0 + sseg);
                *(uint4*)&As[sm][sseg]     = p[0];
                *(uint4*)&As[sm][sseg + 8] = p[1];
            } else {
                uint4 z; z.x = 0; z.y = 0; z.z = 0; z.w = 0;
                *(uint4*)&As[sm][sseg]     = z;
                *(uint4*)&As[sm][sseg + 8] = z;
            }
        }
        {
            *(uint4*)&Bs[bn][bseg] =
                *(const uint4*)(wot + (size_t)(n0 + bn) * 768 + k0 + bseg);
        }
        __syncthreads();

        bf16x8 af0 = *(const bf16x8*)&As[(wave << 5) + l16][quad * 8];
        bf16x8 af1 = *(const bf16x8*)&As[(wave << 5) + 16 + l16][quad * 8];
#pragma unroll
        for (int j = 0; j < 4; ++j) {
            bf16x8 b8 = *(const bf16x8*)&Bs[16 * j + l16][quad * 8];
            acc[0][j] = __builtin_amdgcn_mfma_f32_16x16x32_bf16(af0, b8, acc[0][j], 0, 0, 0);
            acc[1][j] = __builtin_amdgcn_mfma_f32_16x16x32_bf16(af1, b8, acc[1][j], 0, 0, 0);
        }
    }

#pragma unroll
    for (int i = 0; i < 2; ++i) {
#pragma unroll
        for (int reg = 0; reg < 4; ++reg) {
            int gm = m0 + (wave << 5) + (i << 4) + quad * 4 + reg;
            if (gm >= M) continue;
            float* p = out + (size_t)gm * 768;
#pragma unroll
            for (int j = 0; j < 4; ++j) {
                int n = n0 + 16 * j + l16;
                p[n] = acc[i][j][reg] + bo[n];
            }
        }
    }
}

extern "C" void kernel_launch(void* const* d_in, const int* in_sizes, int n_in,
                              void* d_out, int out_size, void* d_ws, size_t ws_size,
                              hipStream_t stream) {
    const float* x  = (const float*)d_in[0];
    const float* wq = (const float*)d_in[1];
    const float* bq = (const float*)d_in[2];
    const float* wk = (const float*)d_in[3];
    const float* bk = (const float*)d_in[4];
    const float* wv = (const float*)d_in[5];
    const float* bv = (const float*)d_in[6];
    const float* wo = (const float*)d_in[7];
    const float* bo = (const float*)d_in[8];
    const float* tp = (const float*)d_in[9];
    float* out = (float*)d_out;

    const size_t per = (size_t)BB * HH * LQ * DD;  // 12,595,200 elements
    const size_t wsz = (size_t)FF * FF;            // 589,824 elements
    u16* ws16  = (u16*)d_ws;
    u16* qbuf  = ws16;
    u16* kbuf  = qbuf + per;
    u16* vbuf  = kbuf + per;          // V from QKV GEMM; reused as obuf in attn
    u16* xb    = vbuf + per;          // x bf16; reused as vtbuf after gemm_qkv
    u16* wqt   = xb + per;            // dead after gemm_qkv (vtbuf spills here)
    u16* wkt   = wqt + wsz;
    u16* wvt   = wkt + wsz;
    u16* wot   = wvt + wsz;           // must survive until gemm_out (untouched)
    float* tpa = (float*)(wot + wsz); // 12*TPSTRIDE floats

    u16* vtbuf = xb;                  // 192*64*VSTRIDE = 12,779,520 <= per + wsz
    u16* obuf  = vbuf;

    convert_x<<<2048, 256, 0, stream>>>(x, xb, (int)(per / 4));
    dim3 gt(12, 12, 4);
    transpose_w<<<gt, 256, 0, stream>>>(wq, wk, wv, wo, wqt, wkt, wvt, wot);
    build_tpa<<<(HH * TPSTRIDE + 255) / 256, 256, 0, stream>>>(tp, tpa);

    dim3 g1(129, 12);
    gemm_qkv_mfma<<<g1, 256, 0, stream>>>(xb, wqt, wkt, wvt, bq, bk, bv,
                                          qbuf, kbuf, vbuf);

    dim3 gv(17, BB * HH);
    transpose_v<<<gv, 256, 0, stream>>>(vbuf, vtbuf);

    dim3 g2(17, BB * HH);
    attn_fused<<<g2, 256, 0, stream>>>(qbuf, kbuf, vtbuf, tpa, obuf);

    dim3 g3(129, 12);
    gemm_out_mfma<<<g3, 256, 0, stream>>>(obuf, wot, bo, out);
}

// Round 8
// 481.737 us; speedup vs baseline: 13.5027x; 1.0063x over previous
//
#include <hip/hip_runtime.h>
#include <hip/hip_bf16.h>

#define BB 16
#define LQ 1025
#define FF 768
#define HH 12
#define DD 64
#define EPSF 1e-8f

#define TPSTRIDE 6400     // per-head mask table: [0,64)=0, [64,4160)=|tp|, [4160,6400)=1
#define QPART_CLS 6270    // CLS-query qpart -> all reads land in the ones band
#define VSTRIDE 1040      // vtbuf key stride (16B aligned, >=1025, zero-padded)

typedef unsigned short u16;
typedef __attribute__((ext_vector_type(8))) short  bf16x8;
typedef __attribute__((ext_vector_type(4))) float  f32x4;

__device__ __forceinline__ float bf2f(u16 u) {
    union { unsigned int i; float f; } c;
    c.i = ((unsigned int)u) << 16;
    return c.f;
}

__device__ __forceinline__ u16 f2bf(float f) {
    union { float f; unsigned int i; } c;
    c.f = f;
    unsigned int x = c.i;
    unsigned int r = (x + 0x7fffu + ((x >> 16) & 1u)) >> 16;  // round-nearest-even
    return (u16)r;
}

// ---------------------------------------------------------------------------
// Pre-pass A: convert x (fp32) -> xb (bf16).
// ---------------------------------------------------------------------------
__global__ __launch_bounds__(256) void convert_x(
    const float* __restrict__ x, u16* __restrict__ xb, int n4)
{
    int i = blockIdx.x * blockDim.x + threadIdx.x;
    const int stride = gridDim.x * blockDim.x;
    for (; i < n4; i += stride) {
        float4 f = ((const float4*)x)[i];
        ushort4 o;
        o.x = f2bf(f.x); o.y = f2bf(f.y); o.z = f2bf(f.z); o.w = f2bf(f.w);
        ((ushort4*)xb)[i] = o;
    }
}

// ---------------------------------------------------------------------------
// Pre-pass B: transpose+convert the four 768x768 weight matrices to bf16.
// ---------------------------------------------------------------------------
__global__ __launch_bounds__(256) void transpose_w(
    const float* __restrict__ wq, const float* __restrict__ wk,
    const float* __restrict__ wv, const float* __restrict__ wo,
    u16* __restrict__ wqt, u16* __restrict__ wkt,
    u16* __restrict__ wvt, u16* __restrict__ wot)
{
    const int z = blockIdx.z;
    const float* __restrict__ src = (z == 0) ? wq : (z == 1) ? wk : (z == 2) ? wv : wo;
    u16* __restrict__ dst         = (z == 0) ? wqt : (z == 1) ? wkt : (z == 2) ? wvt : wot;

    const int c0 = blockIdx.x * 64;
    const int r0 = blockIdx.y * 64;

    __shared__ u16 tile[64][72];

    const int t   = threadIdx.x;
    const int row = t >> 2;
    const int cs  = (t & 3) << 4;

    {
        const float* p = src + (size_t)(r0 + row) * 768 + c0 + cs;
#pragma unroll
        for (int q = 0; q < 4; ++q) {
            float4 f = *(const float4*)(p + 4 * q);
            ushort4 o;
            o.x = f2bf(f.x); o.y = f2bf(f.y); o.z = f2bf(f.z); o.w = f2bf(f.w);
            *(ushort4*)&tile[row][cs + 4 * q] = o;
        }
    }
    __syncthreads();
    {
        u16* p = dst + (size_t)(c0 + row) * 768 + r0 + cs;
#pragma unroll
        for (int q = 0; q < 4; ++q) {
            ushort4 o;
            o.x = tile[cs + 4 * q + 0][row];
            o.y = tile[cs + 4 * q + 1][row];
            o.z = tile[cs + 4 * q + 2][row];
            o.w = tile[cs + 4 * q + 3][row];
            *(ushort4*)(p + 4 * q) = o;
        }
    }
}

// ---------------------------------------------------------------------------
// Pre-pass C: mask table tpa[h][TPSTRIDE] ([0,64)=0, mid=|tp|, tail=1).
// ---------------------------------------------------------------------------
__global__ __launch_bounds__(256) void build_tpa(
    const float* __restrict__ tp, float* __restrict__ tpa)
{
    int i = blockIdx.x * 256 + threadIdx.x;
    if (i >= HH * TPSTRIDE) return;
    int h = i / TPSTRIDE, j = i - h * TPSTRIDE;
    float v;
    if (j < 64) v = 0.f;
    else if (j < 64 + 4096) v = fabsf(tp[h * 4096 + (j - 64)]);
    else v = 1.f;
    tpa[i] = v;
}

// ---------------------------------------------------------------------------
// Pre-pass C2: pack biases [bq|bk|bv] -> bias_cat[2304].
// ---------------------------------------------------------------------------
__global__ __launch_bounds__(256) void pack_bias(
    const float* __restrict__ bq, const float* __restrict__ bk,
    const float* __restrict__ bv, float* __restrict__ bias_cat)
{
    int i = blockIdx.x * 256 + threadIdx.x;
    if (i >= 2304) return;
    float v = (i < 768) ? bq[i] : (i < 1536) ? bk[i - 768] : bv[i - 1536];
    bias_cat[i] = v;
}

// ---------------------------------------------------------------------------
// Pre-pass D: transpose V per (b,h): vbuf [bh][l][d] -> vtbuf [bh][d][VSTRIDE].
// ---------------------------------------------------------------------------
__global__ __launch_bounds__(256) void transpose_v(
    const u16* __restrict__ vbuf, u16* __restrict__ vtbuf)
{
    const int bh = blockIdx.y;
    const int lt = blockIdx.x;           // 0..16
    __shared__ u16 tile[64][65];
    const int t   = threadIdx.x;
    const int row = t >> 2;              // 0..63
    const int seg = (t & 3) << 4;        // 0,16,32,48

    {
        int l = lt * 64 + row;
        if (l < LQ) {
            const ushort4* p = (const ushort4*)(vbuf + ((size_t)bh * LQ + l) * 64 + seg);
#pragma unroll
            for (int q = 0; q < 4; ++q) {
                ushort4 a = p[q];
                tile[row][seg + 4 * q + 0] = a.x;
                tile[row][seg + 4 * q + 1] = a.y;
                tile[row][seg + 4 * q + 2] = a.z;
                tile[row][seg + 4 * q + 3] = a.w;
            }
        } else {
#pragma unroll
            for (int j = 0; j < 16; ++j) tile[row][seg + j] = 0;
        }
    }
    __syncthreads();
    {
        int kbase = lt * 64 + seg;
        if (kbase + 16 <= VSTRIDE) {
            u16* q = vtbuf + (size_t)bh * 64 * VSTRIDE + (size_t)row * VSTRIDE + kbase;
#pragma unroll
            for (int g = 0; g < 4; ++g) {
                ushort4 o;
                o.x = tile[seg + 4 * g + 0][row];
                o.y = tile[seg + 4 * g + 1][row];
                o.z = tile[seg + 4 * g + 2][row];
                o.w = tile[seg + 4 * g + 3][row];
                *(ushort4*)(q + 4 * g) = o;
            }
        }
    }
}

// ---------------------------------------------------------------------------
// Kernel 1: merged QKV projection on MFMA.
//   A = xb [M][768]; B = wt [2304][768] (wqt|wkt|wvt contiguous, [n][k]).
//   Block 256 = 4 waves, tile 128x128, per-wave 64x64, BK=32.
//   Type (q/k/v) is block-uniform (n-tile boundaries align with 768-splits).
// ---------------------------------------------------------------------------
__global__ __launch_bounds__(256) void gemm_qkv_mfma(
    const u16* __restrict__ xb, const u16* __restrict__ wt,
    const float* __restrict__ bias_cat,
    u16* __restrict__ qbuf, u16* __restrict__ kbuf, u16* __restrict__ vbuf)
{
    const int M   = BB * LQ;
    const int m0  = blockIdx.x * 128;
    const int n0g = blockIdx.y * 128;          // global n in [0,2304)

    __shared__ u16 As[128][40];
    __shared__ u16 Bs[128][40];

    const int t    = threadIdx.x;
    const int wave = t >> 6;
    const int lane = t & 63;
    const int quad = lane >> 4;
    const int l16  = lane & 15;
    const int wm   = (wave >> 1) << 6;         // 0,64
    const int wn   = (wave & 1) << 6;          // 0,64

    const int sm   = t >> 1;                   // 0..127
    const int sseg = (t & 1) << 4;             // 0,16

    f32x4 acc[4][4];
#pragma unroll
    for (int i = 0; i < 4; ++i)
#pragma unroll
        for (int j = 0; j < 4; ++j)
            acc[i][j] = (f32x4){0.f, 0.f, 0.f, 0.f};

    for (int k0 = 0; k0 < 768; k0 += 32) {
        __syncthreads();
        {
            int gm = m0 + sm;
            if (gm < M) {
                const uint4* p = (const uint4*)(xb + (size_t)gm * 768 + k0 + sseg);
                *(uint4*)&As[sm][sseg]     = p[0];
                *(uint4*)&As[sm][sseg + 8] = p[1];
            } else {
                uint4 z; z.x = 0; z.y = 0; z.z = 0; z.w = 0;
                *(uint4*)&As[sm][sseg]     = z;
                *(uint4*)&As[sm][sseg + 8] = z;
            }
        }
        {
            const uint4* p = (const uint4*)(wt + (size_t)(n0g + sm) * 768 + k0 + sseg);
            *(uint4*)&Bs[sm][sseg]     = p[0];
            *(uint4*)&Bs[sm][sseg + 8] = p[1];
        }
        __syncthreads();

        bf16x8 af[4], bf[4];
#pragma unroll
        for (int i = 0; i < 4; ++i) af[i] = *(const bf16x8*)&As[wm + 16 * i + l16][quad * 8];
#pragma unroll
        for (int j = 0; j < 4; ++j) bf[j] = *(const bf16x8*)&Bs[wn + 16 * j + l16][quad * 8];
#pragma unroll
        for (int i = 0; i < 4; ++i)
#pragma unroll
            for (int j = 0; j < 4; ++j)
                acc[i][j] = __builtin_amdgcn_mfma_f32_16x16x32_bf16(af[i], bf[j], acc[i][j], 0, 0, 0);
    }

    // epilogue (type block-uniform)
    const int type = (n0g >= 1536) ? 2 : (n0g >= 768) ? 1 : 0;
    u16* __restrict__ outb = (type == 0) ? qbuf : (type == 1) ? kbuf : vbuf;
    const int nbase = n0g - type * 768;

#pragma unroll
    for (int i = 0; i < 4; ++i) {
#pragma unroll
        for (int reg = 0; reg < 4; ++reg) {
            int gm = m0 + wm + 16 * i + quad * 4 + reg;
            if (gm >= M) continue;
            int b_idx = gm / LQ;
            int l     = gm - b_idx * LQ;
#pragma unroll
            for (int j = 0; j < 4; ++j) {
                int nloc = nbase + wn + 16 * j + l16;   // 0..767 within matrix
                int h = nloc >> 6, d = nloc & 63;
                float v = acc[i][j][reg] + bias_cat[n0g + wn + 16 * j + l16];
                if (type == 0) v = fmaxf(v * 0.125f, 0.f) + EPSF;
                else if (type == 1) v = fmaxf(v, 0.f) + EPSF;
                outb[((size_t)(b_idx * HH + h) * LQ + l) * 64 + d] = f2bf(v);
            }
        }
    }
}

// ---------------------------------------------------------------------------
// Kernel 2: fused attention, v4 — double-buffered K/V, 1 barrier per k-tile.
//   S^T = K.Q^T MFMA, table-driven mask (idx ladder -128/tile), register
//   prefetch 2 tiles ahead, pre-transposed V. S tile rows are wave-private
//   (no barrier needed between S write and PV read).
// ---------------------------------------------------------------------------
__global__ __launch_bounds__(256) void attn_fused(
    const u16* __restrict__ qbuf, const u16* __restrict__ kbuf,
    const u16* __restrict__ vtbuf, const float* __restrict__ tpa,
    u16* __restrict__ obuf)
{
    const int bh = blockIdx.y;
    const int b  = bh / HH;
    const int h  = bh - b * HH;
    const int q0 = blockIdx.x * 64;

    __shared__ u16 SQ[64][72];        // Q tile, then S tile (wave-private rows)
    __shared__ u16 Ks[2][64][72];
    __shared__ u16 Vt[2][64][72];     // [d][key]

    const int t    = threadIdx.x;
    const int wave = t >> 6;
    const int lane = t & 63;
    const int quad = lane >> 4;
    const int l16  = lane & 15;
    const int w16  = wave << 4;

    const size_t base  = (size_t)bh * LQ * 64;
    const size_t vbase = (size_t)bh * 64 * VSTRIDE;
    const float* tb = tpa + h * TPSTRIDE;

    const int srow = t >> 2;          // staging row
    const int sseg = (t & 3) << 4;    // staging seg (u16)

    // ---- stage Q tile (overrun reads land in kbuf, harmless) ----
    {
        const uint4* qp = (const uint4*)(qbuf + base + (size_t)(q0 + srow) * 64 + sseg);
        *(uint4*)&SQ[srow][sseg]     = qp[0];
        *(uint4*)&SQ[srow][sseg + 8] = qp[1];
    }

    // ---- per-lane q metadata ----
    const int qi = q0 + w16 + l16;
    int qpart;
    if (qi == 0) qpart = QPART_CLS;
    else { int qm1 = qi - 1; qpart = (((qm1 >> 5) + 32) << 6) + (qm1 & 31) + 32; }

    int idx[16];
#pragma unroll
    for (int ct = 0; ct < 4; ++ct)
#pragma unroll
        for (int reg = 0; reg < 4; ++reg) {
            int km1 = ct * 16 + quad * 4 + reg - 1;
            idx[ct * 4 + reg] = 64 + qpart - (((km1 >> 5) << 6) + (km1 & 31));
        }

    // ---- prefetch tile 0 into registers ----
    uint4 kr0, kr1, vr0, vr1;
    {
        uint4 z; z.x = 0; z.y = 0; z.z = 0; z.w = 0;
        int ki = srow;
        if (ki < LQ) {
            const uint4* kp = (const uint4*)(kbuf + base + (size_t)ki * 64 + sseg);
            kr0 = kp[0]; kr1 = kp[1];
        } else { kr0 = z; kr1 = z; }
        const uint4* vp = (const uint4*)(vtbuf + vbase + (size_t)srow * VSTRIDE + sseg);
        vr0 = vp[0]; vr1 = vp[1];
    }

    __syncthreads();   // Q staged

    bf16x8 qf0 = *(const bf16x8*)&SQ[w16 + l16][quad * 8];
    bf16x8 qf1 = *(const bf16x8*)&SQ[w16 + l16][32 + quad * 8];

    // write tile 0 into buffer 0
    *(uint4*)&Ks[0][srow][sseg]     = kr0;
    *(uint4*)&Ks[0][srow][sseg + 8] = kr1;
    *(uint4*)&Vt[0][srow][sseg]     = vr0;
    *(uint4*)&Vt[0][srow][sseg + 8] = vr1;

    // prefetch tile 1
    {
        uint4 z; z.x = 0; z.y = 0; z.z = 0; z.w = 0;
        int ki = 64 + srow;
        if (ki < LQ) {
            const uint4* kp = (const uint4*)(kbuf + base + (size_t)ki * 64 + sseg);
            kr0 = kp[0]; kr1 = kp[1];
        } else { kr0 = z; kr1 = z; }
        int vcol = 64 + sseg;
        const uint4* vp = (const uint4*)(vtbuf + vbase + (size_t)srow * VSTRIDE + vcol);
        vr0 = vp[0]; vr1 = vp[1];
    }

    f32x4 acc_o[4];
#pragma unroll
    for (int dt = 0; dt < 4; ++dt) acc_o[dt] = (f32x4){0.f, 0.f, 0.f, 0.f};
    float den = 0.f;

    __syncthreads();   // buffer 0 visible

    for (int kt = 0; kt < 17; ++kt) {
        const int p = kt & 1;

        // write prefetched tile kt+1 into the idle buffer
        if (kt < 16) {
            *(uint4*)&Ks[p ^ 1][srow][sseg]     = kr0;
            *(uint4*)&Ks[p ^ 1][srow][sseg + 8] = kr1;
            *(uint4*)&Vt[p ^ 1][srow][sseg]     = vr0;
            *(uint4*)&Vt[p ^ 1][srow][sseg + 8] = vr1;
        }
        // prefetch tile kt+2
        if (kt < 15) {
            uint4 z; z.x = 0; z.y = 0; z.z = 0; z.w = 0;
            int k0n = (kt + 2) * 64;
            int ki = k0n + srow;
            if (ki < LQ) {
                const uint4* kp = (const uint4*)(kbuf + base + (size_t)ki * 64 + sseg);
                kr0 = kp[0]; kr1 = kp[1];
            } else { kr0 = z; kr1 = z; }
            int vcol = k0n + sseg;
            if (vcol + 16 <= VSTRIDE) {
                const uint4* vp = (const uint4*)(vtbuf + vbase + (size_t)srow * VSTRIDE + vcol);
                vr0 = vp[0]; vr1 = vp[1];
            } else { vr0 = z; vr1 = z; }
        }

        // tm gather (overlaps MFMAs)
        float tmv[16];
#pragma unroll
        for (int e = 0; e < 16; ++e) tmv[e] = tb[idx[e]];

        // ---- QK^T as S^T = K.Q^T from buffer p ----
        f32x4 acc_s[4];
#pragma unroll
        for (int ct = 0; ct < 4; ++ct) {
            bf16x8 kf0 = *(const bf16x8*)&Ks[p][ct * 16 + l16][quad * 8];
            bf16x8 kf1 = *(const bf16x8*)&Ks[p][ct * 16 + l16][32 + quad * 8];
            f32x4 z = (f32x4){0.f, 0.f, 0.f, 0.f};
            z = __builtin_amdgcn_mfma_f32_16x16x32_bf16(kf0, qf0, z, 0, 0, 0);
            z = __builtin_amdgcn_mfma_f32_16x16x32_bf16(kf1, qf1, z, 0, 0, 0);
            acc_s[ct] = z;
        }

        if (kt == 0) { if (quad == 0) tmv[0] = 1.0f; }   // CLS key

        // ---- mask + eps + den + S write (wave-private rows) ----
#pragma unroll
        for (int ct = 0; ct < 4; ++ct) {
            float s0 = acc_s[ct][0] * tmv[ct * 4 + 0] + EPSF;
            float s1 = acc_s[ct][1] * tmv[ct * 4 + 1] + EPSF;
            float s2 = acc_s[ct][2] * tmv[ct * 4 + 2] + EPSF;
            float s3 = acc_s[ct][3] * tmv[ct * 4 + 3] + EPSF;
            den += (s0 + s1) + (s2 + s3);
            ushort4 w;
            w.x = f2bf(s0); w.y = f2bf(s1); w.z = f2bf(s2); w.w = f2bf(s3);
            *(ushort4*)&SQ[w16 + l16][ct * 16 + quad * 4] = w;
        }
#pragma unroll
        for (int e = 0; e < 16; ++e) idx[e] -= 128;

        // ---- PV: A = S (own rows, same-wave lgkmcnt), B = Vt[p] ----
        {
            bf16x8 a0 = *(const bf16x8*)&SQ[w16 + l16][quad * 8];
            bf16x8 a1 = *(const bf16x8*)&SQ[w16 + l16][32 + quad * 8];
#pragma unroll
            for (int dt = 0; dt < 4; ++dt) {
                bf16x8 b0 = *(const bf16x8*)&Vt[p][dt * 16 + l16][quad * 8];
                bf16x8 b1 = *(const bf16x8*)&Vt[p][dt * 16 + l16][32 + quad * 8];
                acc_o[dt] = __builtin_amdgcn_mfma_f32_16x16x32_bf16(a0, b0, acc_o[dt], 0, 0, 0);
                acc_o[dt] = __builtin_amdgcn_mfma_f32_16x16x32_bf16(a1, b1, acc_o[dt], 0, 0, 0);
            }
        }

        if (kt < 16) __syncthreads();   // staging visible, everyone done with buf p
    }

    // ---- den across quads ----
    den += __shfl_xor(den, 16);
    den += __shfl_xor(den, 32);
    float invd = 1.f / den;

#pragma unroll
    for (int reg = 0; reg < 4; ++reg) {
        int r = quad * 4 + reg;
        float iv = __shfl(invd, r, 64);
        int qrow = q0 + w16 + r;
        if (qrow < LQ) {
            u16* p = obuf + ((size_t)(b * LQ + qrow) * HH + h) * 64;
#pragma unroll
            for (int dt = 0; dt < 4; ++dt)
                p[dt * 16 + l16] = f2bf(acc_o[dt][reg] * iv);
        }
    }
}

// ---------------------------------------------------------------------------
// Kernel 3: output projection on MFMA, 128x128 tile, 64x64 per wave.
// ---------------------------------------------------------------------------
__global__ __launch_bounds__(256) void gemm_out_mfma(
    const u16* __restrict__ a, const u16* __restrict__ wot,
    const float* __restrict__ bo, float* __restrict__ out)
{
    const int M  = BB * LQ;
    const int m0 = blockIdx.x * 128;
    const int n0 = blockIdx.y * 128;

    __shared__ u16 As[128][40];
    __shared__ u16 Bs[128][40];

    const int t    = threadIdx.x;
    const int wave = t >> 6;
    const int lane = t & 63;
    const int quad = lane >> 4;
    const int l16  = lane & 15;
    const int wm   = (wave >> 1) << 6;
    const int wn   = (wave & 1) << 6;

    const int sm   = t >> 1;
    const int sseg = (t & 1) << 4;

    f32x4 acc[4][4];
#pragma unroll
    for (int i = 0; i < 4; ++i)
#pragma unroll
        for (int j = 0; j < 4; ++j)
            acc[i][j] = (f32x4){0.f, 0.f, 0.f, 0.f};

    for (int k0 = 0; k0 < 768; k0 += 32) {
        __syncthreads();
        {
            int gm = m0 + sm;
            if (gm < M) {
                const uint4* p = (const uint4*)(a + (size_t)gm * 768 + k0 + sseg);
                *(uint4*)&As[sm][sseg]     = p[0];
                *(uint4*)&As[sm][sseg + 8] = p[1];
            } else {
                uint4 z; z.x = 0; z.y = 0; z.z = 0; z.w = 0;
                *(uint4*)&As[sm][sseg]     = z;
                *(uint4*)&As[sm][sseg + 8] = z;
            }
        }
        {
            const uint4* p = (const uint4*)(wot + (size_t)(n0 + sm) * 768 + k0 + sseg);
            *(uint4*)&Bs[sm][sseg]     = p[0];
            *(uint4*)&Bs[sm][sseg + 8] = p[1];
        }
        __syncthreads();

        bf16x8 af[4], bf[4];
#pragma unroll
        for (int i = 0; i < 4; ++i) af[i] = *(const bf16x8*)&As[wm + 16 * i + l16][quad * 8];
#pragma unroll
        for (int j = 0; j < 4; ++j) bf[j] = *(const bf16x8*)&Bs[wn + 16 * j + l16][quad * 8];
#pragma unroll
        for (int i = 0; i < 4; ++i)
#pragma unroll
            for (int j = 0; j < 4; ++j)
                acc[i][j] = __builtin_amdgcn_mfma_f32_16x16x32_bf16(af[i], bf[j], acc[i][j], 0, 0, 0);
    }

#pragma unroll
    for (int i = 0; i < 4; ++i) {
#pragma unroll
        for (int reg = 0; reg < 4; ++reg) {
            int gm = m0 + wm + 16 * i + quad * 4 + reg;
            if (gm >= M) continue;
            float* p = out + (size_t)gm * 768;
#pragma unroll
            for (int j = 0; j < 4; ++j) {
                int n = n0 + wn + 16 * j + l16;
                p[n] = acc[i][j][reg] + bo[n];
            }
        }
    }
}

extern "C" void kernel_launch(void* const* d_in, const int* in_sizes, int n_in,
                              void* d_out, int out_size, void* d_ws, size_t ws_size,
                              hipStream_t stream) {
    const float* x  = (const float*)d_in[0];
    const float* wq = (const float*)d_in[1];
    const float* bq = (const float*)d_in[2];
    const float* wk = (const float*)d_in[3];
    const float* bk = (const float*)d_in[4];
    const float* wv = (const float*)d_in[5];
    const float* bv = (const float*)d_in[6];
    const float* wo = (const float*)d_in[7];
    const float* bo = (const float*)d_in[8];
    const float* tp = (const float*)d_in[9];
    float* out = (float*)d_out;

    const size_t per = (size_t)BB * HH * LQ * DD;  // 12,595,200 elements
    const size_t wsz = (size_t)FF * FF;            // 589,824 elements
    u16* ws16  = (u16*)d_ws;
    u16* qbuf  = ws16;
    u16* kbuf  = qbuf + per;
    u16* vbuf  = kbuf + per;          // V from QKV GEMM; reused as obuf in attn
    u16* xb    = vbuf + per;          // x bf16; reused as vtbuf after gemm_qkv
    u16* wqt   = xb + per;            // wqt|wkt|wvt contiguous = merged wt
    u16* wkt   = wqt + wsz;
    u16* wvt   = wkt + wsz;
    u16* wot   = wvt + wsz;           // survives until gemm_out
    float* tpa = (float*)(wot + wsz); // 12*TPSTRIDE floats
    float* bias_cat = tpa + HH * TPSTRIDE;  // 2304 floats

    u16* vtbuf = xb;                  // 192*64*VSTRIDE spills into dead wqt region
    u16* obuf  = vbuf;

    convert_x<<<2048, 256, 0, stream>>>(x, xb, (int)(per / 4));
    dim3 gt(12, 12, 4);
    transpose_w<<<gt, 256, 0, stream>>>(wq, wk, wv, wo, wqt, wkt, wvt, wot);
    build_tpa<<<(HH * TPSTRIDE + 255) / 256, 256, 0, stream>>>(tp, tpa);
    pack_bias<<<9, 256, 0, stream>>>(bq, bk, bv, bias_cat);

    dim3 g1(129, 18);
    gemm_qkv_mfma<<<g1, 256, 0, stream>>>(xb, wqt, bias_cat, qbuf, kbuf, vbuf);

    dim3 gv(17, BB * HH);
    transpose_v<<<gv, 256, 0, stream>>>(vbuf, vtbuf);

    dim3 g2(17, BB * HH);
    attn_fused<<<g2, 256, 0, stream>>>(qbuf, kbuf, vtbuf, tpa, obuf);

    dim3 g3(129, 6);
    gemm_out_mfma<<<g3, 256, 0, stream>>>(obuf, wot, bo, out);
}